// Round 1
// baseline (1987.110 us; speedup 1.0000x reference)
//
#include <hip/hip_runtime.h>
#include <cstdint>
#include <cstddef>

#define B 4
#define NN 32768
#define NE 262144
#define CV 16
#define CE 16
#define HID 64
#define CM 48   // 2*CV + CE

__device__ __forceinline__ float fast_tanh(float x) {
    // tanh(x) = 1 - 2/(exp(2x)+1); safe at +/-inf (no NaN)
    float e = __expf(2.0f * x);
    return 1.0f - 2.0f / (e + 1.0f);
}

// ---------------- degree counts ----------------
__global__ __launch_bounds__(256) void count_kernel(
    const int* __restrict__ ca, const int* __restrict__ cb,
    int* __restrict__ cnt_a, int* __restrict__ cnt_b)
{
    int i = blockIdx.x * 256 + threadIdx.x;
    if (i < NE) {
        atomicAdd(&cnt_a[ca[i]], 1);
        atomicAdd(&cnt_b[cb[i]], 1);
    }
}

// ---------------- edge MLP + scatter ----------------
__global__ __launch_bounds__(256) void edge_kernel(
    const float* __restrict__ node_vals, const float* __restrict__ edge_vals,
    const int* __restrict__ ca, const int* __restrict__ cb,
    const float* __restrict__ Wm1, const float* __restrict__ bm1,
    const float* __restrict__ Wm2, const float* __restrict__ bm2,
    float* __restrict__ out_edge,
    float* __restrict__ agg_a, float* __restrict__ agg_b)
{
    __shared__ float sW1[HID * CM];   // transposed: sW1[k*CM+i] = Wm1[i*HID+k]
    __shared__ float sW2[HID * CM];   // sW2[k*CM+j] = Wm2[k*CM+j]
    __shared__ float sb1[HID];
    __shared__ float sb2[CM];

    int t = threadIdx.x;
    for (int x = t; x < HID * CM; x += 256) {
        int k = x / CM, i = x - k * CM;
        sW1[x] = Wm1[i * HID + k];
        sW2[x] = Wm2[x];
    }
    if (t < HID) sb1[t] = bm1[t];
    if (t < CM)  sb2[t] = bm2[t];
    __syncthreads();

    int idx = blockIdx.x * 256 + t;          // idx = b*NE + e
    int e = idx & (NE - 1);
    int b = idx >> 18;
    int na = ca[e], nb = cb[e];

    float h[CM];
    const float4* pA = (const float4*)(node_vals + ((size_t)b * NN + na) * CV);
    const float4* pB = (const float4*)(node_vals + ((size_t)b * NN + nb) * CV);
    const float4* pE = (const float4*)(edge_vals + (size_t)idx * CE);
#pragma unroll
    for (int q = 0; q < 4; q++) {
        float4 va = pA[q];
        h[q*4+0] = va.x; h[q*4+1] = va.y; h[q*4+2] = va.z; h[q*4+3] = va.w;
        float4 vb = pB[q];
        h[16+q*4+0] = vb.x; h[16+q*4+1] = vb.y; h[16+q*4+2] = vb.z; h[16+q*4+3] = vb.w;
        float4 ve = pE[q];
        h[32+q*4+0] = ve.x; h[32+q*4+1] = ve.y; h[32+q*4+2] = ve.z; h[32+q*4+3] = ve.w;
    }

    float m[CM];
#pragma unroll
    for (int j = 0; j < CM; j++) m[j] = sb2[j];

    for (int k = 0; k < HID; k++) {
        float acc = sb1[k];
        const float* w1 = &sW1[k * CM];
#pragma unroll
        for (int i = 0; i < CM; i++) acc = fmaf(h[i], w1[i], acc);
        float th = fast_tanh(acc);
        const float* w2 = &sW2[k * CM];
#pragma unroll
        for (int j = 0; j < CM; j++) m[j] = fmaf(th, w2[j], m[j]);
    }

    // new_edge_vals = edge_vals + m[32:48]
    float4* oe = (float4*)(out_edge + (size_t)idx * CE);
#pragma unroll
    for (int q = 0; q < 4; q++) {
        oe[q] = make_float4(h[32+q*4+0] + m[32+q*4+0],
                            h[32+q*4+1] + m[32+q*4+1],
                            h[32+q*4+2] + m[32+q*4+2],
                            h[32+q*4+3] + m[32+q*4+3]);
    }

    // scatter-add m_a -> agg_a[b, na], m_b -> agg_b[b, nb]
    float* pa = agg_a + ((size_t)b * NN + na) * CV;
    float* pb = agg_b + ((size_t)b * NN + nb) * CV;
#pragma unroll
    for (int c = 0; c < CV; c++) atomicAdd(&pa[c], m[c]);
#pragma unroll
    for (int c = 0; c < CV; c++) atomicAdd(&pb[c], m[CV + c]);
}

// ---------------- node MLP + residual ----------------
__global__ __launch_bounds__(256) void node_kernel(
    const float* __restrict__ node_vals,
    const float* __restrict__ agg_a, const float* __restrict__ agg_b,
    const int* __restrict__ cnt_a, const int* __restrict__ cnt_b,
    const float* __restrict__ Wu1, const float* __restrict__ bu1,
    const float* __restrict__ Wu2, const float* __restrict__ bu2,
    float* __restrict__ out_node)
{
    __shared__ float sW1[HID * CM];   // sW1[k*CM+i] = Wu1[i*HID+k]
    __shared__ float sW2[HID * CV];   // sW2[k*CV+j] = Wu2[k*CV+j]
    __shared__ float sb1[HID];
    __shared__ float sb2[CV];

    int t = threadIdx.x;
    for (int x = t; x < HID * CM; x += 256) {
        int k = x / CM, i = x - k * CM;
        sW1[x] = Wu1[i * HID + k];
    }
    for (int x = t; x < HID * CV; x += 256) sW2[x] = Wu2[x];
    if (t < HID) sb1[t] = bu1[t];
    if (t < CV)  sb2[t] = bu2[t];
    __syncthreads();

    int idx = blockIdx.x * 256 + t;          // idx = b*NN + n
    int n = idx & (NN - 1);

    float ra = 1.0f / fmaxf((float)cnt_a[n], 1.0f);
    float rb = 1.0f / fmaxf((float)cnt_b[n], 1.0f);

    float u[CM];
    const float4* pa = (const float4*)(agg_a + (size_t)idx * CV);
    const float4* pb = (const float4*)(agg_b + (size_t)idx * CV);
    const float4* pn = (const float4*)(node_vals + (size_t)idx * CV);
#pragma unroll
    for (int q = 0; q < 4; q++) {
        float4 va = pa[q];
        u[q*4+0] = va.x * ra; u[q*4+1] = va.y * ra; u[q*4+2] = va.z * ra; u[q*4+3] = va.w * ra;
        float4 vb = pb[q];
        u[16+q*4+0] = vb.x * rb; u[16+q*4+1] = vb.y * rb; u[16+q*4+2] = vb.z * rb; u[16+q*4+3] = vb.w * rb;
        float4 vn = pn[q];
        u[32+q*4+0] = vn.x; u[32+q*4+1] = vn.y; u[32+q*4+2] = vn.z; u[32+q*4+3] = vn.w;
    }

    float o[CV];
#pragma unroll
    for (int j = 0; j < CV; j++) o[j] = sb2[j];

    for (int k = 0; k < HID; k++) {
        float acc = sb1[k];
        const float* w1 = &sW1[k * CM];
#pragma unroll
        for (int i = 0; i < CM; i++) acc = fmaf(u[i], w1[i], acc);
        float th = fast_tanh(acc);
        const float* w2 = &sW2[k * CV];
#pragma unroll
        for (int j = 0; j < CV; j++) o[j] = fmaf(th, w2[j], o[j]);
    }

    float4* on = (float4*)(out_node + (size_t)idx * CV);
#pragma unroll
    for (int q = 0; q < 4; q++) {
        on[q] = make_float4(u[32+q*4+0] + o[q*4+0],
                            u[32+q*4+1] + o[q*4+1],
                            u[32+q*4+2] + o[q*4+2],
                            u[32+q*4+3] + o[q*4+3]);
    }
}

extern "C" void kernel_launch(void* const* d_in, const int* in_sizes, int n_in,
                              void* d_out, int out_size, void* d_ws, size_t ws_size,
                              hipStream_t stream) {
    const float* node_vals = (const float*)d_in[0];
    const float* edge_vals = (const float*)d_in[1];
    const int*   ca        = (const int*)d_in[2];
    const int*   cb        = (const int*)d_in[3];
    const float* Wm1 = (const float*)d_in[4];
    const float* bm1 = (const float*)d_in[5];
    const float* Wm2 = (const float*)d_in[6];
    const float* bm2 = (const float*)d_in[7];
    const float* Wu1 = (const float*)d_in[8];
    const float* bu1 = (const float*)d_in[9];
    const float* Wu2 = (const float*)d_in[10];
    const float* bu2 = (const float*)d_in[11];

    float* out_node = (float*)d_out;
    float* out_edge = out_node + (size_t)B * NN * CV;   // 2,097,152

    float* agg_a = (float*)d_ws;
    float* agg_b = agg_a + (size_t)B * NN * CV;
    int*   cnt_a = (int*)(agg_b + (size_t)B * NN * CV);
    int*   cnt_b = cnt_a + NN;

    size_t zero_bytes = (2 * (size_t)B * NN * CV) * sizeof(float) + 2 * (size_t)NN * sizeof(int);
    hipMemsetAsync(d_ws, 0, zero_bytes, stream);

    count_kernel<<<NE / 256, 256, 0, stream>>>(ca, cb, cnt_a, cnt_b);
    edge_kernel<<<(B * NE) / 256, 256, 0, stream>>>(
        node_vals, edge_vals, ca, cb, Wm1, bm1, Wm2, bm2, out_edge, agg_a, agg_b);
    node_kernel<<<(B * NN) / 256, 256, 0, stream>>>(
        node_vals, agg_a, agg_b, cnt_a, cnt_b, Wu1, bu1, Wu2, bu2, out_node);
}

// Round 2
// 523.880 us; speedup vs baseline: 3.7931x; 3.7931x over previous
//
#include <hip/hip_runtime.h>
#include <cstdint>
#include <cstddef>

#define B 4
#define NN 32768
#define NE 262144
#define CV 16
#define CE 16
#define HID 64
#define CM 48   // 2*CV + CE

__device__ __forceinline__ float fast_tanh(float x) {
    float e = __expf(2.0f * x);
    return 1.0f - 2.0f / (e + 1.0f);
}

// ---------------- degree counts ----------------
__global__ __launch_bounds__(256) void count_kernel(
    const int* __restrict__ ca, const int* __restrict__ cb,
    int* __restrict__ cnt_a, int* __restrict__ cnt_b)
{
    int i = blockIdx.x * 256 + threadIdx.x;
    if (i < NE) {
        atomicAdd(&cnt_a[ca[i]], 1);
        atomicAdd(&cnt_b[cb[i]], 1);
    }
}

// ---------------- exclusive prefix sum over NN bins (1 block) ----------------
__global__ __launch_bounds__(1024) void scan_kernel(
    const int* __restrict__ cnt, int* __restrict__ start, int* __restrict__ cur)
{
    __shared__ int s[1024];
    int t = threadIdx.x;
    int base = t * 32;
    int local[32];
    int sum = 0;
#pragma unroll
    for (int i = 0; i < 32; i++) { local[i] = cnt[base + i]; sum += local[i]; }
    s[t] = sum;
    __syncthreads();
    // Hillis-Steele inclusive scan over 1024 partials
    for (int off = 1; off < 1024; off <<= 1) {
        int add = (t >= off) ? s[t - off] : 0;
        __syncthreads();
        s[t] += add;
        __syncthreads();
    }
    int run = s[t] - sum;   // exclusive prefix of this thread's chunk
#pragma unroll
    for (int i = 0; i < 32; i++) {
        start[base + i] = run;
        cur[base + i] = run;
        run += local[i];
    }
}

// ---------------- fill CSR edge lists ----------------
__global__ __launch_bounds__(256) void fill_kernel(
    const int* __restrict__ ca, const int* __restrict__ cb,
    int* __restrict__ cur_a, int* __restrict__ cur_b,
    int* __restrict__ eidx_a, int* __restrict__ eidx_b)
{
    int e = blockIdx.x * 256 + threadIdx.x;
    if (e < NE) {
        int pa = atomicAdd(&cur_a[ca[e]], 1);
        eidx_a[pa] = e;
        int pb = atomicAdd(&cur_b[cb[e]], 1);
        eidx_b[pb] = e;
    }
}

// ---------------- edge MLP: write m_a,m_b to m_buf; fused edge residual ----------------
__global__ __launch_bounds__(256) void edge_kernel(
    const float* __restrict__ node_vals, const float* __restrict__ edge_vals,
    const int* __restrict__ ca, const int* __restrict__ cb,
    const float* __restrict__ Wm1, const float* __restrict__ bm1,
    const float* __restrict__ Wm2, const float* __restrict__ bm2,
    float* __restrict__ out_edge,
    float* __restrict__ m_buf)
{
    __shared__ float sW1[HID * CM];   // transposed: sW1[k*CM+i] = Wm1[i*HID+k]
    __shared__ float sW2[HID * CM];   // sW2[k*CM+j] = Wm2[k*CM+j]
    __shared__ float sb1[HID];
    __shared__ float sb2[CM];

    int t = threadIdx.x;
    for (int x = t; x < HID * CM; x += 256) {
        int k = x / CM, i = x - k * CM;
        sW1[x] = Wm1[i * HID + k];
        sW2[x] = Wm2[x];
    }
    if (t < HID) sb1[t] = bm1[t];
    if (t < CM)  sb2[t] = bm2[t];
    __syncthreads();

    int idx = blockIdx.x * 256 + t;          // idx = b*NE + e
    int e = idx & (NE - 1);
    int b = idx >> 18;
    int na = ca[e], nb = cb[e];

    float h[CM];
    const float4* pA = (const float4*)(node_vals + ((size_t)b * NN + na) * CV);
    const float4* pB = (const float4*)(node_vals + ((size_t)b * NN + nb) * CV);
    const float4* pE = (const float4*)(edge_vals + (size_t)idx * CE);
#pragma unroll
    for (int q = 0; q < 4; q++) {
        float4 va = pA[q];
        h[q*4+0] = va.x; h[q*4+1] = va.y; h[q*4+2] = va.z; h[q*4+3] = va.w;
        float4 vb = pB[q];
        h[16+q*4+0] = vb.x; h[16+q*4+1] = vb.y; h[16+q*4+2] = vb.z; h[16+q*4+3] = vb.w;
        float4 ve = pE[q];
        h[32+q*4+0] = ve.x; h[32+q*4+1] = ve.y; h[32+q*4+2] = ve.z; h[32+q*4+3] = ve.w;
    }

    float m[CM];
#pragma unroll
    for (int j = 0; j < CM; j++) m[j] = sb2[j];

    for (int k = 0; k < HID; k++) {
        float acc = sb1[k];
        const float* w1 = &sW1[k * CM];
#pragma unroll
        for (int i = 0; i < CM; i++) acc = fmaf(h[i], w1[i], acc);
        float th = fast_tanh(acc);
        const float* w2 = &sW2[k * CM];
#pragma unroll
        for (int j = 0; j < CM; j++) m[j] = fmaf(th, w2[j], m[j]);
    }

    // m_a, m_b -> m_buf[idx][0:32]  (128B contiguous per edge)
    float4* mb = (float4*)(m_buf + (size_t)idx * 32);
#pragma unroll
    for (int q = 0; q < 8; q++) {
        mb[q] = make_float4(m[q*4+0], m[q*4+1], m[q*4+2], m[q*4+3]);
    }

    // new_edge_vals = edge_vals + m[32:48]
    float4* oe = (float4*)(out_edge + (size_t)idx * CE);
#pragma unroll
    for (int q = 0; q < 4; q++) {
        oe[q] = make_float4(h[32+q*4+0] + m[32+q*4+0],
                            h[32+q*4+1] + m[32+q*4+1],
                            h[32+q*4+2] + m[32+q*4+2],
                            h[32+q*4+3] + m[32+q*4+3]);
    }
}

// ---------------- gather-aggregate: 16 lanes per (b,node) ----------------
__global__ __launch_bounds__(256) void agg_kernel(
    const float* __restrict__ m_buf,
    const int* __restrict__ eidx_a, const int* __restrict__ eidx_b,
    const int* __restrict__ start_a, const int* __restrict__ start_b,
    const int* __restrict__ cnt_a, const int* __restrict__ cnt_b,
    float* __restrict__ agg_a, float* __restrict__ agg_b)
{
    int t = threadIdx.x;
    int team = t >> 4;          // 16 teams per block
    int c = t & 15;             // channel
    int g = blockIdx.x * 16 + team;   // g = b*NN + n
    int n = g & (NN - 1);
    int b = g >> 15;
    size_t mb_base = (size_t)b * NE * 32;

    int da = cnt_a[n];
    int sa = start_a[n];
    float suma = 0.0f;
    for (int k = 0; k < da; k++) {
        int e = eidx_a[sa + k];
        suma += m_buf[mb_base + (size_t)e * 32 + c];
    }
    agg_a[(size_t)g * CV + c] = suma / (float)max(da, 1);

    int db = cnt_b[n];
    int sb = start_b[n];
    float sumb = 0.0f;
    for (int k = 0; k < db; k++) {
        int e = eidx_b[sb + k];
        sumb += m_buf[mb_base + (size_t)e * 32 + 16 + c];
    }
    agg_b[(size_t)g * CV + c] = sumb / (float)max(db, 1);
}

// ---------------- node MLP + residual ----------------
__global__ __launch_bounds__(256) void node_kernel(
    const float* __restrict__ node_vals,
    const float* __restrict__ agg_a, const float* __restrict__ agg_b,
    const float* __restrict__ Wu1, const float* __restrict__ bu1,
    const float* __restrict__ Wu2, const float* __restrict__ bu2,
    float* __restrict__ out_node)
{
    __shared__ float sW1[HID * CM];   // sW1[k*CM+i] = Wu1[i*HID+k]
    __shared__ float sW2[HID * CV];   // sW2[k*CV+j] = Wu2[k*CV+j]
    __shared__ float sb1[HID];
    __shared__ float sb2[CV];

    int t = threadIdx.x;
    for (int x = t; x < HID * CM; x += 256) {
        int k = x / CM, i = x - k * CM;
        sW1[x] = Wu1[i * HID + k];
    }
    for (int x = t; x < HID * CV; x += 256) sW2[x] = Wu2[x];
    if (t < HID) sb1[t] = bu1[t];
    if (t < CV)  sb2[t] = bu2[t];
    __syncthreads();

    int idx = blockIdx.x * 256 + t;          // idx = b*NN + n

    float u[CM];
    const float4* pa = (const float4*)(agg_a + (size_t)idx * CV);
    const float4* pb = (const float4*)(agg_b + (size_t)idx * CV);
    const float4* pn = (const float4*)(node_vals + (size_t)idx * CV);
#pragma unroll
    for (int q = 0; q < 4; q++) {
        float4 va = pa[q];
        u[q*4+0] = va.x; u[q*4+1] = va.y; u[q*4+2] = va.z; u[q*4+3] = va.w;
        float4 vb = pb[q];
        u[16+q*4+0] = vb.x; u[16+q*4+1] = vb.y; u[16+q*4+2] = vb.z; u[16+q*4+3] = vb.w;
        float4 vn = pn[q];
        u[32+q*4+0] = vn.x; u[32+q*4+1] = vn.y; u[32+q*4+2] = vn.z; u[32+q*4+3] = vn.w;
    }

    float o[CV];
#pragma unroll
    for (int j = 0; j < CV; j++) o[j] = sb2[j];

    for (int k = 0; k < HID; k++) {
        float acc = sb1[k];
        const float* w1 = &sW1[k * CM];
#pragma unroll
        for (int i = 0; i < CM; i++) acc = fmaf(u[i], w1[i], acc);
        float th = fast_tanh(acc);
        const float* w2 = &sW2[k * CV];
#pragma unroll
        for (int j = 0; j < CV; j++) o[j] = fmaf(th, w2[j], o[j]);
    }

    float4* on = (float4*)(out_node + (size_t)idx * CV);
#pragma unroll
    for (int q = 0; q < 4; q++) {
        on[q] = make_float4(u[32+q*4+0] + o[q*4+0],
                            u[32+q*4+1] + o[q*4+1],
                            u[32+q*4+2] + o[q*4+2],
                            u[32+q*4+3] + o[q*4+3]);
    }
}

extern "C" void kernel_launch(void* const* d_in, const int* in_sizes, int n_in,
                              void* d_out, int out_size, void* d_ws, size_t ws_size,
                              hipStream_t stream) {
    const float* node_vals = (const float*)d_in[0];
    const float* edge_vals = (const float*)d_in[1];
    const int*   ca        = (const int*)d_in[2];
    const int*   cb        = (const int*)d_in[3];
    const float* Wm1 = (const float*)d_in[4];
    const float* bm1 = (const float*)d_in[5];
    const float* Wm2 = (const float*)d_in[6];
    const float* bm2 = (const float*)d_in[7];
    const float* Wu1 = (const float*)d_in[8];
    const float* bu1 = (const float*)d_in[9];
    const float* Wu2 = (const float*)d_in[10];
    const float* bu2 = (const float*)d_in[11];

    float* out_node = (float*)d_out;
    float* out_edge = out_node + (size_t)B * NN * CV;

    // ws layout
    float* m_buf = (float*)d_ws;                          // B*NE*32 floats (128 MB)
    float* agg_a = m_buf + (size_t)B * NE * 32;           // B*NN*CV (8 MB)
    float* agg_b = agg_a + (size_t)B * NN * CV;           // 8 MB
    int* cnt_a   = (int*)(agg_b + (size_t)B * NN * CV);
    int* cnt_b   = cnt_a + NN;
    int* start_a = cnt_b + NN;
    int* start_b = start_a + NN;
    int* cur_a   = start_b + NN;
    int* cur_b   = cur_a + NN;
    int* eidx_a  = cur_b + NN;
    int* eidx_b  = eidx_a + NE;

    // only the histogram counters need zeroing
    hipMemsetAsync(cnt_a, 0, 2 * (size_t)NN * sizeof(int), stream);

    count_kernel<<<NE / 256, 256, 0, stream>>>(ca, cb, cnt_a, cnt_b);
    scan_kernel<<<1, 1024, 0, stream>>>(cnt_a, start_a, cur_a);
    scan_kernel<<<1, 1024, 0, stream>>>(cnt_b, start_b, cur_b);
    fill_kernel<<<NE / 256, 256, 0, stream>>>(ca, cb, cur_a, cur_b, eidx_a, eidx_b);
    edge_kernel<<<(B * NE) / 256, 256, 0, stream>>>(
        node_vals, edge_vals, ca, cb, Wm1, bm1, Wm2, bm2, out_edge, m_buf);
    agg_kernel<<<(B * NN) / 16, 256, 0, stream>>>(
        m_buf, eidx_a, eidx_b, start_a, start_b, cnt_a, cnt_b, agg_a, agg_b);
    node_kernel<<<(B * NN) / 256, 256, 0, stream>>>(
        node_vals, agg_a, agg_b, Wu1, bu1, Wu2, bu2, out_node);
}

// Round 4
// 422.788 us; speedup vs baseline: 4.7000x; 1.2391x over previous
//
#include <hip/hip_runtime.h>
#include <hip/hip_bf16.h>
#include <cstdint>
#include <cstddef>

#define B 4
#define NN 32768
#define NE 262144
#define CV 16
#define CE 16
#define HID 64
#define CM 48   // 2*CV + CE
#define HS 72   // LDS row stride in bf16 elems (144 B: 16B-aligned rows, odd dword count)

using frag  = __attribute__((ext_vector_type(8))) short;
using f32x4 = __attribute__((ext_vector_type(4))) float;

__device__ __forceinline__ float fast_tanh(float x) {
    float e = __expf(2.0f * x);
    return 1.0f - 2.0f / (e + 1.0f);
}

__device__ __forceinline__ unsigned short f2bf(float x) {
    union { float f; unsigned u; } v; v.f = x;
    unsigned r = (v.u + 0x7FFFu + ((v.u >> 16) & 1u)) >> 16;
    return (unsigned short)r;
}

__device__ __forceinline__ float bf2f(unsigned short x) {
    union { unsigned u; float f; } v; v.u = ((unsigned)x) << 16;
    return v.f;
}

// ---------------- degree counts ----------------
__global__ __launch_bounds__(256) void count_kernel(
    const int* __restrict__ ca, const int* __restrict__ cb,
    int* __restrict__ cnt_a, int* __restrict__ cnt_b)
{
    int i = blockIdx.x * 256 + threadIdx.x;
    if (i < NE) {
        atomicAdd(&cnt_a[ca[i]], 1);
        atomicAdd(&cnt_b[cb[i]], 1);
    }
}

// ---------------- exclusive prefix sum over NN bins (2 blocks: a and b) ----------------
__global__ __launch_bounds__(1024) void scan_kernel(
    const int* __restrict__ cnt_a, int* __restrict__ start_a, int* __restrict__ cur_a,
    const int* __restrict__ cnt_b, int* __restrict__ start_b, int* __restrict__ cur_b)
{
    const int* cnt = (blockIdx.x == 0) ? cnt_a : cnt_b;
    int* start     = (blockIdx.x == 0) ? start_a : start_b;
    int* cur       = (blockIdx.x == 0) ? cur_a : cur_b;

    __shared__ int s[1024];
    int t = threadIdx.x;
    int base = t * 32;
    int local[32];
    int sum = 0;
#pragma unroll
    for (int i = 0; i < 32; i++) { local[i] = cnt[base + i]; sum += local[i]; }
    s[t] = sum;
    __syncthreads();
    for (int off = 1; off < 1024; off <<= 1) {
        int add = (t >= off) ? s[t - off] : 0;
        __syncthreads();
        s[t] += add;
        __syncthreads();
    }
    int run = s[t] - sum;
#pragma unroll
    for (int i = 0; i < 32; i++) {
        start[base + i] = run;
        cur[base + i] = run;
        run += local[i];
    }
}

// ---------------- fill CSR edge lists ----------------
__global__ __launch_bounds__(256) void fill_kernel(
    const int* __restrict__ ca, const int* __restrict__ cb,
    int* __restrict__ cur_a, int* __restrict__ cur_b,
    int* __restrict__ eidx_a, int* __restrict__ eidx_b)
{
    int e = blockIdx.x * 256 + threadIdx.x;
    if (e < NE) {
        int pa = atomicAdd(&cur_a[ca[e]], 1);
        eidx_a[pa] = e;
        int pb = atomicAdd(&cur_b[cb[e]], 1);
        eidx_b[pb] = e;
    }
}

// ---------------- edge MLP via bf16 MFMA ----------------
// Block = 256 edges, 4 waves; wave w owns edge-rows [w*64, w*64+64).
// GEMM1: H[256x64] @ W1[64x64] (K padded 48->64, bias folded at k=48)
// tanh -> LDS (C-layout -> A-layout round trip, barrier-protected),
// GEMM2: T[256x64] @ W2[64x48].
__global__ __launch_bounds__(256) void edge_kernel(
    const float* __restrict__ node_vals, const float* __restrict__ edge_vals,
    const int* __restrict__ ca, const int* __restrict__ cb,
    const float* __restrict__ Wm1, const float* __restrict__ bm1,
    const float* __restrict__ Wm2, const float* __restrict__ bm2,
    float* __restrict__ out_edge,
    unsigned short* __restrict__ m_buf16)
{
    __shared__ unsigned short sH[256 * HS];   // H, then reused for T
    __shared__ unsigned short sW1[64 * HS];   // W1t[n][k] = Wm1[k][n]; k=48 -> bm1
    __shared__ unsigned short sW2[48 * HS];   // W2t[n][k] = Wm2[k][n]
    __shared__ float sb2f[CM];

    int t = threadIdx.x;

    // ---- stage weights ----
    for (int x = t; x < 64 * 64; x += 256) {
        int n = x >> 6, k = x & 63;
        float w = (k < 48) ? Wm1[k * 64 + n] : (k == 48 ? bm1[n] : 0.0f);
        sW1[n * HS + k] = f2bf(w);
    }
    for (int x = t; x < 48 * 64; x += 256) {
        int n = x >> 6, k = x & 63;
        sW2[n * HS + k] = f2bf(Wm2[k * 48 + n]);
    }
    if (t < CM) sb2f[t] = bm2[t];

    // ---- stage H: thread t gathers edge (blk*256 + t) ----
    size_t eb = (size_t)blockIdx.x * 256;
    {
        size_t idx = eb + t;
        int e = (int)(idx & (NE - 1));
        int b = (int)(idx >> 18);
        int na = ca[e], nb = cb[e];
        float h[48];
        const float4* pA = (const float4*)(node_vals + ((size_t)b * NN + na) * CV);
        const float4* pB = (const float4*)(node_vals + ((size_t)b * NN + nb) * CV);
        const float4* pE = (const float4*)(edge_vals + idx * CE);
#pragma unroll
        for (int q = 0; q < 4; q++) {
            float4 va = pA[q];
            h[q*4+0] = va.x; h[q*4+1] = va.y; h[q*4+2] = va.z; h[q*4+3] = va.w;
            float4 vb = pB[q];
            h[16+q*4+0] = vb.x; h[16+q*4+1] = vb.y; h[16+q*4+2] = vb.z; h[16+q*4+3] = vb.w;
            float4 ve = pE[q];
            h[32+q*4+0] = ve.x; h[32+q*4+1] = ve.y; h[32+q*4+2] = ve.z; h[32+q*4+3] = ve.w;
        }
        unsigned pk[32];
#pragma unroll
        for (int q = 0; q < 24; q++)
            pk[q] = (unsigned)f2bf(h[2*q]) | ((unsigned)f2bf(h[2*q+1]) << 16);
        pk[24] = 0x3F80u;   // col 48 = 1.0 (bias), col 49 = 0
#pragma unroll
        for (int q = 25; q < 32; q++) pk[q] = 0;
        uint4* row = (uint4*)&sH[t * HS];
        const uint4* src = (const uint4*)pk;
#pragma unroll
        for (int q = 0; q < 8; q++) row[q] = src[q];
    }
    __syncthreads();   // H + weights ready

    int lane = t & 63;
    int wv   = t >> 6;
    int col  = lane & 15;
    int quad = lane >> 4;
    int mbase = wv * 64;

    // ---- GEMM1: acc1[mt][nt] = H @ W1 ----
    f32x4 acc1[4][4];
#pragma unroll
    for (int mt = 0; mt < 4; mt++)
#pragma unroll
        for (int nt = 0; nt < 4; nt++) acc1[mt][nt] = (f32x4){0.f, 0.f, 0.f, 0.f};

#pragma unroll
    for (int ks = 0; ks < 2; ks++) {
        frag a[4], b[4];
#pragma unroll
        for (int mt = 0; mt < 4; mt++)
            a[mt] = *(const frag*)&sH[(mbase + mt*16 + col) * HS + ks*32 + quad*8];
#pragma unroll
        for (int nt = 0; nt < 4; nt++)
            b[nt] = *(const frag*)&sW1[(nt*16 + col) * HS + ks*32 + quad*8];
#pragma unroll
        for (int mt = 0; mt < 4; mt++)
#pragma unroll
            for (int nt = 0; nt < 4; nt++)
                acc1[mt][nt] = __builtin_amdgcn_mfma_f32_16x16x32_bf16(a[mt], b[nt], acc1[mt][nt], 0, 0, 0);
    }

    // ---- tanh, C-layout -> A-layout via LDS ----
    // Barrier-protected: ensures every wave's GEMM1 reads of sH are complete
    // (lgkmcnt drained) before sH is overwritten, and all writes are complete
    // before GEMM2 reads. The round-3 single-barrier version raced here.
    __syncthreads();
#pragma unroll
    for (int mt = 0; mt < 4; mt++)
#pragma unroll
        for (int nt = 0; nt < 4; nt++)
#pragma unroll
            for (int r = 0; r < 4; r++) {
                int m = mbase + mt*16 + quad*4 + r;
                int n = nt*16 + col;
                sH[m * HS + n] = f2bf(fast_tanh(acc1[mt][nt][r]));
            }
    __syncthreads();

    // ---- GEMM2: acc2[mt][nt] = T @ W2 ----
    f32x4 acc2[4][3];
#pragma unroll
    for (int mt = 0; mt < 4; mt++)
#pragma unroll
        for (int nt = 0; nt < 3; nt++) acc2[mt][nt] = (f32x4){0.f, 0.f, 0.f, 0.f};

#pragma unroll
    for (int ks = 0; ks < 2; ks++) {
        frag a[4], b[3];
#pragma unroll
        for (int mt = 0; mt < 4; mt++)
            a[mt] = *(const frag*)&sH[(mbase + mt*16 + col) * HS + ks*32 + quad*8];
#pragma unroll
        for (int nt = 0; nt < 3; nt++)
            b[nt] = *(const frag*)&sW2[(nt*16 + col) * HS + ks*32 + quad*8];
#pragma unroll
        for (int mt = 0; mt < 4; mt++)
#pragma unroll
            for (int nt = 0; nt < 3; nt++)
                acc2[mt][nt] = __builtin_amdgcn_mfma_f32_16x16x32_bf16(a[mt], b[nt], acc2[mt][nt], 0, 0, 0);
    }

    // ---- epilogue ----
    // nt 0,1 -> m_a,m_b into m_buf16 (bf16); nt 2 -> edge residual (fp32)
#pragma unroll
    for (int mt = 0; mt < 4; mt++) {
#pragma unroll
        for (int nt = 0; nt < 2; nt++) {
#pragma unroll
            for (int r = 0; r < 4; r++) {
                int m = mbase + mt*16 + quad*4 + r;
                int j = nt*16 + col;
                float val = acc2[mt][nt][r] + sb2f[j];
                m_buf16[(eb + m) * 32 + j] = f2bf(val);
            }
        }
#pragma unroll
        for (int r = 0; r < 4; r++) {
            int m = mbase + mt*16 + quad*4 + r;
            int c = col;  // j = 32 + col
            float val = acc2[mt][2][r] + sb2f[32 + c];
            size_t o = (eb + m) * CE + c;
            out_edge[o] = edge_vals[o] + val;
        }
    }
}

// ---------------- gather-aggregate: 32 lanes per (b,node): 16 for a, 16 for b ----------------
__global__ __launch_bounds__(256) void agg_kernel(
    const unsigned short* __restrict__ m_buf16,
    const int* __restrict__ eidx_a, const int* __restrict__ eidx_b,
    const int* __restrict__ start_a, const int* __restrict__ start_b,
    const int* __restrict__ cnt_a, const int* __restrict__ cnt_b,
    float* __restrict__ agg_a, float* __restrict__ agg_b)
{
    int t = threadIdx.x;
    int team = t >> 5;            // 8 nodes per block
    int half = (t >> 4) & 1;      // 0 = a-endpoint, 1 = b-endpoint
    int c = t & 15;
    int g = blockIdx.x * 8 + team;   // g = b*NN + n
    int n = g & (NN - 1);
    int b = g >> 15;

    const int* eidx  = half ? eidx_b  : eidx_a;
    const int* stp   = half ? start_b : start_a;
    const int* cntp  = half ? cnt_b   : cnt_a;
    float* aggp      = half ? agg_b   : agg_a;

    int d = cntp[n];
    int s = stp[n];
    size_t mb = (size_t)b * NE * 32 + half * 16 + c;
    float sum = 0.0f;
    for (int k = 0; k < d; k++) {
        int e = eidx[s + k];
        sum += bf2f(m_buf16[mb + (size_t)e * 32]);
    }
    aggp[(size_t)g * CV + c] = sum / (float)max(d, 1);
}

// ---------------- node MLP + residual ----------------
__global__ __launch_bounds__(256) void node_kernel(
    const float* __restrict__ node_vals,
    const float* __restrict__ agg_a, const float* __restrict__ agg_b,
    const float* __restrict__ Wu1, const float* __restrict__ bu1,
    const float* __restrict__ Wu2, const float* __restrict__ bu2,
    float* __restrict__ out_node)
{
    __shared__ float sW1[HID * CM];
    __shared__ float sW2[HID * CV];
    __shared__ float sb1[HID];
    __shared__ float sb2[CV];

    int t = threadIdx.x;
    for (int x = t; x < HID * CM; x += 256) {
        int k = x / CM, i = x - k * CM;
        sW1[x] = Wu1[i * HID + k];
    }
    for (int x = t; x < HID * CV; x += 256) sW2[x] = Wu2[x];
    if (t < HID) sb1[t] = bu1[t];
    if (t < CV)  sb2[t] = bu2[t];
    __syncthreads();

    int idx = blockIdx.x * 256 + t;

    float u[CM];
    const float4* pa = (const float4*)(agg_a + (size_t)idx * CV);
    const float4* pb = (const float4*)(agg_b + (size_t)idx * CV);
    const float4* pn = (const float4*)(node_vals + (size_t)idx * CV);
#pragma unroll
    for (int q = 0; q < 4; q++) {
        float4 va = pa[q];
        u[q*4+0] = va.x; u[q*4+1] = va.y; u[q*4+2] = va.z; u[q*4+3] = va.w;
        float4 vb = pb[q];
        u[16+q*4+0] = vb.x; u[16+q*4+1] = vb.y; u[16+q*4+2] = vb.z; u[16+q*4+3] = vb.w;
        float4 vn = pn[q];
        u[32+q*4+0] = vn.x; u[32+q*4+1] = vn.y; u[32+q*4+2] = vn.z; u[32+q*4+3] = vn.w;
    }

    float o[CV];
#pragma unroll
    for (int j = 0; j < CV; j++) o[j] = sb2[j];

    for (int k = 0; k < HID; k++) {
        float acc = sb1[k];
        const float* w1 = &sW1[k * CM];
#pragma unroll
        for (int i = 0; i < CM; i++) acc = fmaf(u[i], w1[i], acc);
        float th = fast_tanh(acc);
        const float* w2 = &sW2[k * CV];
#pragma unroll
        for (int j = 0; j < CV; j++) o[j] = fmaf(th, w2[j], o[j]);
    }

    float4* on = (float4*)(out_node + (size_t)idx * CV);
#pragma unroll
    for (int q = 0; q < 4; q++) {
        on[q] = make_float4(u[32+q*4+0] + o[q*4+0],
                            u[32+q*4+1] + o[q*4+1],
                            u[32+q*4+2] + o[q*4+2],
                            u[32+q*4+3] + o[q*4+3]);
    }
}

extern "C" void kernel_launch(void* const* d_in, const int* in_sizes, int n_in,
                              void* d_out, int out_size, void* d_ws, size_t ws_size,
                              hipStream_t stream) {
    const float* node_vals = (const float*)d_in[0];
    const float* edge_vals = (const float*)d_in[1];
    const int*   ca        = (const int*)d_in[2];
    const int*   cb        = (const int*)d_in[3];
    const float* Wm1 = (const float*)d_in[4];
    const float* bm1 = (const float*)d_in[5];
    const float* Wm2 = (const float*)d_in[6];
    const float* bm2 = (const float*)d_in[7];
    const float* Wu1 = (const float*)d_in[8];
    const float* bu1 = (const float*)d_in[9];
    const float* Wu2 = (const float*)d_in[10];
    const float* bu2 = (const float*)d_in[11];

    float* out_node = (float*)d_out;
    float* out_edge = out_node + (size_t)B * NN * CV;

    // ws layout
    unsigned short* m_buf16 = (unsigned short*)d_ws;              // B*NE*32 bf16 (64 MB)
    float* agg_a = (float*)(m_buf16 + (size_t)B * NE * 32);       // 8 MB
    float* agg_b = agg_a + (size_t)B * NN * CV;                   // 8 MB
    int* cnt_a   = (int*)(agg_b + (size_t)B * NN * CV);
    int* cnt_b   = cnt_a + NN;
    int* start_a = cnt_b + NN;
    int* start_b = start_a + NN;
    int* cur_a   = start_b + NN;
    int* cur_b   = cur_a + NN;
    int* eidx_a  = cur_b + NN;
    int* eidx_b  = eidx_a + NE;

    hipMemsetAsync(cnt_a, 0, 2 * (size_t)NN * sizeof(int), stream);

    count_kernel<<<NE / 256, 256, 0, stream>>>(ca, cb, cnt_a, cnt_b);
    scan_kernel<<<2, 1024, 0, stream>>>(cnt_a, start_a, cur_a, cnt_b, start_b, cur_b);
    fill_kernel<<<NE / 256, 256, 0, stream>>>(ca, cb, cur_a, cur_b, eidx_a, eidx_b);
    edge_kernel<<<(B * NE) / 256, 256, 0, stream>>>(
        node_vals, edge_vals, ca, cb, Wm1, bm1, Wm2, bm2, out_edge, m_buf16);
    agg_kernel<<<(B * NN) / 8, 256, 0, stream>>>(
        m_buf16, eidx_a, eidx_b, start_a, start_b, cnt_a, cnt_b, agg_a, agg_b);
    node_kernel<<<(B * NN) / 256, 256, 0, stream>>>(
        node_vals, agg_a, agg_b, Wu1, bu1, Wu2, bu2, out_node);
}

// Round 5
// 362.447 us; speedup vs baseline: 5.4825x; 1.1665x over previous
//
#include <hip/hip_runtime.h>
#include <hip/hip_bf16.h>
#include <cstdint>
#include <cstddef>

#define B 4
#define NN 32768
#define NE 262144
#define CV 16
#define CE 16
#define HID 64
#define CM 48   // 2*CV + CE
#define HS 72   // LDS row stride in bf16 elems (144 B; cols 64..71 unused -> pos stash)

using frag  = __attribute__((ext_vector_type(8))) short;
using f32x4 = __attribute__((ext_vector_type(4))) float;

__device__ __forceinline__ float fast_tanh(float x) {
    float e = __expf(2.0f * x);
    return 1.0f - 2.0f / (e + 1.0f);
}

__device__ __forceinline__ unsigned short f2bf(float x) {
    union { float f; unsigned u; } v; v.f = x;
    unsigned r = (v.u + 0x7FFFu + ((v.u >> 16) & 1u)) >> 16;
    return (unsigned short)r;
}

__device__ __forceinline__ float bf2f(unsigned short x) {
    union { unsigned u; float f; } v; v.u = ((unsigned)x) << 16;
    return v.f;
}

// pack two floats -> bf16x2 (v_cvt_pk_bf16_f32 on gfx950 via hip_bf16)
__device__ __forceinline__ unsigned pk2bf(float lo, float hi) {
    union { __hip_bfloat162 h; unsigned u; } v;
    v.h = __float22bfloat162_rn(make_float2(lo, hi));
    return v.u;
}

// ---------------- degree counts + per-edge rank ----------------
__global__ __launch_bounds__(256) void count_kernel(
    const int* __restrict__ ca, const int* __restrict__ cb,
    int* __restrict__ cnt_a, int* __restrict__ cnt_b,
    int* __restrict__ rank_a, int* __restrict__ rank_b)
{
    int i = blockIdx.x * 256 + threadIdx.x;
    rank_a[i] = atomicAdd(&cnt_a[ca[i]], 1);
    rank_b[i] = atomicAdd(&cnt_b[cb[i]], 1);
}

// ---------------- exclusive prefix sum over NN bins (2 blocks: a and b) ----------------
__global__ __launch_bounds__(1024) void scan_kernel(
    const int* __restrict__ cnt_a, int* __restrict__ start_a,
    const int* __restrict__ cnt_b, int* __restrict__ start_b)
{
    const int* cnt = (blockIdx.x == 0) ? cnt_a : cnt_b;
    int* start     = (blockIdx.x == 0) ? start_a : start_b;

    __shared__ int s[1024];
    int t = threadIdx.x;
    int base = t * 32;
    int local[32];
    int sum = 0;
#pragma unroll
    for (int i = 0; i < 32; i++) { local[i] = cnt[base + i]; sum += local[i]; }
    s[t] = sum;
    __syncthreads();
    for (int off = 1; off < 1024; off <<= 1) {
        int add = (t >= off) ? s[t - off] : 0;
        __syncthreads();
        s[t] += add;
        __syncthreads();
    }
    int run = s[t] - sum;
#pragma unroll
    for (int i = 0; i < 32; i++) {
        start[base + i] = run;
        run += local[i];
    }
}

// ---------------- edge MLP via bf16 MFMA (transposed: weights = A operand) ----------------
// Block = 256 edges (one batch b), 4 waves; wave w owns edges [w*64, w*64+64).
// GEMM1: D1[hid][edge] = W1t[64x64] @ Ht ; tanh -> T[edge][hid] in LDS (8B writes);
// GEMM2: D2[ch48][edge] = W2t[48x64] @ Tt.
// C-layout col=lane&15 -> edge, row=quad*4+r -> 4 consecutive channels => packed stores.
__global__ __launch_bounds__(256) void edge_kernel(
    const float* __restrict__ node_vals, const float* __restrict__ edge_vals,
    const int* __restrict__ ca, const int* __restrict__ cb,
    const int* __restrict__ rank_a, const int* __restrict__ rank_b,
    const int* __restrict__ start_a, const int* __restrict__ start_b,
    const float* __restrict__ Wm1, const float* __restrict__ bm1,
    const float* __restrict__ Wm2, const float* __restrict__ bm2,
    float* __restrict__ out_edge,
    unsigned short* __restrict__ ma_csr, unsigned short* __restrict__ mb_csr)
{
    __shared__ unsigned short sH[256 * HS];   // H rows=edges, k-contig; cols 64..67 = pos pair
    __shared__ unsigned short sW1[64 * HS];   // sW1[m=hid][k] = Wm1[k][m]; k=48 -> bm1
    __shared__ unsigned short sW2[48 * HS];   // sW2[m=ch][k]  = Wm2[k][m]
    __shared__ float sb2f[CM];

    int t = threadIdx.x;

    // ---- stage weights ----
    for (int x = t; x < 64 * 64; x += 256) {
        int m = x >> 6, k = x & 63;
        float w = (k < 48) ? Wm1[k * 64 + m] : (k == 48 ? bm1[m] : 0.0f);
        sW1[m * HS + k] = f2bf(w);
    }
    for (int x = t; x < 48 * 64; x += 256) {
        int m = x >> 6, k = x & 63;
        sW2[m * HS + k] = f2bf(Wm2[k * 48 + m]);
    }
    if (t < CM) sb2f[t] = bm2[t];

    // ---- stage H + CSR positions: thread t owns edge (blk*256 + t) ----
    size_t eb = (size_t)blockIdx.x * 256;
    {
        size_t idx = eb + t;
        int e = (int)(idx & (NE - 1));
        int bb = (int)(idx >> 18);
        int na = ca[e], nb = cb[e];
        float h[48];
        const float4* pA = (const float4*)(node_vals + ((size_t)bb * NN + na) * CV);
        const float4* pB = (const float4*)(node_vals + ((size_t)bb * NN + nb) * CV);
        const float4* pE = (const float4*)(edge_vals + idx * CE);
#pragma unroll
        for (int q = 0; q < 4; q++) {
            float4 va = pA[q];
            h[q*4+0] = va.x; h[q*4+1] = va.y; h[q*4+2] = va.z; h[q*4+3] = va.w;
            float4 vb = pB[q];
            h[16+q*4+0] = vb.x; h[16+q*4+1] = vb.y; h[16+q*4+2] = vb.z; h[16+q*4+3] = vb.w;
            float4 ve = pE[q];
            h[32+q*4+0] = ve.x; h[32+q*4+1] = ve.y; h[32+q*4+2] = ve.z; h[32+q*4+3] = ve.w;
        }
        unsigned pk[32];
#pragma unroll
        for (int q = 0; q < 24; q++) pk[q] = pk2bf(h[2*q], h[2*q+1]);
        pk[24] = 0x3F80u;   // k=48: 1.0 (bias row), k=49: 0
#pragma unroll
        for (int q = 25; q < 32; q++) pk[q] = 0;
        uint4* row = (uint4*)&sH[t * HS];
        const uint4* src = (const uint4*)pk;
#pragma unroll
        for (int q = 0; q < 8; q++) row[q] = src[q];
        // stash CSR positions in the row tail (bytes 128..135)
        int2 pos; pos.x = start_a[na] + rank_a[e]; pos.y = start_b[nb] + rank_b[e];
        *(int2*)&sH[t * HS + 64] = pos;
    }
    __syncthreads();   // H + weights + pos ready

    int lane = t & 63;
    int wv   = t >> 6;
    int col  = lane & 15;   // edge within tile
    int quad = lane >> 4;
    int erow = wv * 64;     // wave's edge base within block

    // ---- GEMM1: D1[m=hid][n=edge] ----
    f32x4 acc1[4][4];   // [mt(hid)][nt(edge)]
#pragma unroll
    for (int mt = 0; mt < 4; mt++)
#pragma unroll
        for (int nt = 0; nt < 4; nt++) acc1[mt][nt] = (f32x4){0.f, 0.f, 0.f, 0.f};

#pragma unroll
    for (int ks = 0; ks < 2; ks++) {
        frag a[4], b[4];
#pragma unroll
        for (int mt = 0; mt < 4; mt++)
            a[mt] = *(const frag*)&sW1[(mt*16 + col) * HS + ks*32 + quad*8];
#pragma unroll
        for (int nt = 0; nt < 4; nt++)
            b[nt] = *(const frag*)&sH[(erow + nt*16 + col) * HS + ks*32 + quad*8];
#pragma unroll
        for (int mt = 0; mt < 4; mt++)
#pragma unroll
            for (int nt = 0; nt < 4; nt++)
                acc1[mt][nt] = __builtin_amdgcn_mfma_f32_16x16x32_bf16(a[mt], b[nt], acc1[mt][nt], 0, 0, 0);
    }

    __syncthreads();   // all GEMM1 reads of sH complete before overwrite

    // ---- tanh -> T[edge][hid] in LDS (k cols 0..63 only; pos tail preserved) ----
#pragma unroll
    for (int nt = 0; nt < 4; nt++) {
        int row = erow + nt*16 + col;
#pragma unroll
        for (int mt = 0; mt < 4; mt++) {
            uint2 w;
            w.x = pk2bf(fast_tanh(acc1[mt][nt][0]), fast_tanh(acc1[mt][nt][1]));
            w.y = pk2bf(fast_tanh(acc1[mt][nt][2]), fast_tanh(acc1[mt][nt][3]));
            *(uint2*)&sH[row * HS + mt*16 + quad*4] = w;
        }
    }
    __syncthreads();   // T writes complete before GEMM2 reads

    // ---- GEMM2: D2[m=ch48][n=edge] ----
    f32x4 acc2[3][4];
#pragma unroll
    for (int mt = 0; mt < 3; mt++)
#pragma unroll
        for (int nt = 0; nt < 4; nt++) acc2[mt][nt] = (f32x4){0.f, 0.f, 0.f, 0.f};

#pragma unroll
    for (int ks = 0; ks < 2; ks++) {
        frag a[3], b[4];
#pragma unroll
        for (int mt = 0; mt < 3; mt++)
            a[mt] = *(const frag*)&sW2[(mt*16 + col) * HS + ks*32 + quad*8];
#pragma unroll
        for (int nt = 0; nt < 4; nt++)
            b[nt] = *(const frag*)&sH[(erow + nt*16 + col) * HS + ks*32 + quad*8];
#pragma unroll
        for (int mt = 0; mt < 3; mt++)
#pragma unroll
            for (int nt = 0; nt < 4; nt++)
                acc2[mt][nt] = __builtin_amdgcn_mfma_f32_16x16x32_bf16(a[mt], b[nt], acc2[mt][nt], 0, 0, 0);
    }

    // ---- epilogue: lane = one edge per nt, 4 consecutive channels ----
    int bb = (int)(eb >> 18);           // batch (block-uniform)
    int cha = quad * 4;
#pragma unroll
    for (int nt = 0; nt < 4; nt++) {
        int le = erow + nt*16 + col;    // local edge 0..255
        int2 pos = *(const int2*)&sH[le * HS + 64];

        // m_a -> ma_csr[b][pos.x][cha..cha+3]
        uint2 wa;
        wa.x = pk2bf(acc2[0][nt][0] + sb2f[cha+0], acc2[0][nt][1] + sb2f[cha+1]);
        wa.y = pk2bf(acc2[0][nt][2] + sb2f[cha+2], acc2[0][nt][3] + sb2f[cha+3]);
        *(uint2*)&ma_csr[((size_t)bb * NE + pos.x) * 16 + cha] = wa;

        // m_b -> mb_csr[b][pos.y][cha..cha+3]
        uint2 wb;
        wb.x = pk2bf(acc2[1][nt][0] + sb2f[16+cha+0], acc2[1][nt][1] + sb2f[16+cha+1]);
        wb.y = pk2bf(acc2[1][nt][2] + sb2f[16+cha+2], acc2[1][nt][3] + sb2f[16+cha+3]);
        *(uint2*)&mb_csr[((size_t)bb * NE + pos.y) * 16 + cha] = wb;

        // edge residual (fp32, perfectly coalesced float4)
        size_t o = (eb + le) * CE + cha;
        float4 ev = *(const float4*)&edge_vals[o];
        float4 ov;
        ov.x = ev.x + acc2[2][nt][0] + sb2f[32+cha+0];
        ov.y = ev.y + acc2[2][nt][1] + sb2f[32+cha+1];
        ov.z = ev.z + acc2[2][nt][2] + sb2f[32+cha+2];
        ov.w = ev.w + acc2[2][nt][3] + sb2f[32+cha+3];
        *(float4*)&out_edge[o] = ov;
    }
}

// ---------------- segmented mean over contiguous CSR messages ----------------
// Block 256 = 8 teams x 32 lanes; team = one (b,n); half 0=a,1=b (16 lanes each).
// Lane l16 = e_off*4 + cg: reads 8B (4 ch) of edge s+k*4+e_off -> 128B/iter contiguous.
__global__ __launch_bounds__(256) void agg_kernel(
    const unsigned short* __restrict__ ma_csr, const unsigned short* __restrict__ mb_csr,
    const int* __restrict__ start_a, const int* __restrict__ start_b,
    const int* __restrict__ cnt_a, const int* __restrict__ cnt_b,
    float* __restrict__ agg_a, float* __restrict__ agg_b)
{
    int t = threadIdx.x;
    int team = t >> 5;
    int half = (t >> 4) & 1;
    int l16  = t & 15;
    int e_off = l16 >> 2;
    int cg    = l16 & 3;
    int g = blockIdx.x * 8 + team;      // g = b*NN + n
    int n = g & (NN - 1);
    int b = g >> 15;

    const unsigned short* mcsr = half ? mb_csr : ma_csr;
    const int* stp  = half ? start_b : start_a;
    const int* cntp = half ? cnt_b   : cnt_a;
    float* aggp     = half ? agg_b   : agg_a;

    int d = cntp[n];
    int s = stp[n];
    const unsigned short* base = mcsr + ((size_t)b * NE + s) * 16 + cg * 4;

    float s0 = 0.f, s1 = 0.f, s2 = 0.f, s3 = 0.f;
    for (int k = e_off; k < d; k += 4) {
        uint2 v = *(const uint2*)(base + (size_t)k * 16);
        s0 += bf2f((unsigned short)(v.x & 0xFFFFu));
        s1 += bf2f((unsigned short)(v.x >> 16));
        s2 += bf2f((unsigned short)(v.y & 0xFFFFu));
        s3 += bf2f((unsigned short)(v.y >> 16));
    }
    // reduce across the 4 e_off sub-accumulators (lanes xor 4, 8 stay in 16-group)
    s0 += __shfl_xor(s0, 4); s1 += __shfl_xor(s1, 4);
    s2 += __shfl_xor(s2, 4); s3 += __shfl_xor(s3, 4);
    s0 += __shfl_xor(s0, 8); s1 += __shfl_xor(s1, 8);
    s2 += __shfl_xor(s2, 8); s3 += __shfl_xor(s3, 8);

    if (e_off == 0) {
        float inv = 1.0f / (float)max(d, 1);
        float4 r;
        r.x = s0 * inv; r.y = s1 * inv; r.z = s2 * inv; r.w = s3 * inv;
        *(float4*)&aggp[(size_t)g * CV + cg * 4] = r;
    }
}

// ---------------- node MLP + residual ----------------
__global__ __launch_bounds__(256) void node_kernel(
    const float* __restrict__ node_vals,
    const float* __restrict__ agg_a, const float* __restrict__ agg_b,
    const float* __restrict__ Wu1, const float* __restrict__ bu1,
    const float* __restrict__ Wu2, const float* __restrict__ bu2,
    float* __restrict__ out_node)
{
    __shared__ float sW1[HID * CM];
    __shared__ float sW2[HID * CV];
    __shared__ float sb1[HID];
    __shared__ float sb2[CV];

    int t = threadIdx.x;
    for (int x = t; x < HID * CM; x += 256) {
        int k = x / CM, i = x - k * CM;
        sW1[x] = Wu1[i * HID + k];
    }
    for (int x = t; x < HID * CV; x += 256) sW2[x] = Wu2[x];
    if (t < HID) sb1[t] = bu1[t];
    if (t < CV)  sb2[t] = bu2[t];
    __syncthreads();

    int idx = blockIdx.x * 256 + t;

    float u[CM];
    const float4* pa = (const float4*)(agg_a + (size_t)idx * CV);
    const float4* pb = (const float4*)(agg_b + (size_t)idx * CV);
    const float4* pn = (const float4*)(node_vals + (size_t)idx * CV);
#pragma unroll
    for (int q = 0; q < 4; q++) {
        float4 va = pa[q];
        u[q*4+0] = va.x; u[q*4+1] = va.y; u[q*4+2] = va.z; u[q*4+3] = va.w;
        float4 vb = pb[q];
        u[16+q*4+0] = vb.x; u[16+q*4+1] = vb.y; u[16+q*4+2] = vb.z; u[16+q*4+3] = vb.w;
        float4 vn = pn[q];
        u[32+q*4+0] = vn.x; u[32+q*4+1] = vn.y; u[32+q*4+2] = vn.z; u[32+q*4+3] = vn.w;
    }

    float o[CV];
#pragma unroll
    for (int j = 0; j < CV; j++) o[j] = sb2[j];

    for (int k = 0; k < HID; k++) {
        float acc = sb1[k];
        const float* w1 = &sW1[k * CM];
#pragma unroll
        for (int i = 0; i < CM; i++) acc = fmaf(u[i], w1[i], acc);
        float th = fast_tanh(acc);
        const float* w2 = &sW2[k * CV];
#pragma unroll
        for (int j = 0; j < CV; j++) o[j] = fmaf(th, w2[j], o[j]);
    }

    float4* on = (float4*)(out_node + (size_t)idx * CV);
#pragma unroll
    for (int q = 0; q < 4; q++) {
        on[q] = make_float4(u[32+q*4+0] + o[q*4+0],
                            u[32+q*4+1] + o[q*4+1],
                            u[32+q*4+2] + o[q*4+2],
                            u[32+q*4+3] + o[q*4+3]);
    }
}

extern "C" void kernel_launch(void* const* d_in, const int* in_sizes, int n_in,
                              void* d_out, int out_size, void* d_ws, size_t ws_size,
                              hipStream_t stream) {
    const float* node_vals = (const float*)d_in[0];
    const float* edge_vals = (const float*)d_in[1];
    const int*   ca        = (const int*)d_in[2];
    const int*   cb        = (const int*)d_in[3];
    const float* Wm1 = (const float*)d_in[4];
    const float* bm1 = (const float*)d_in[5];
    const float* Wm2 = (const float*)d_in[6];
    const float* bm2 = (const float*)d_in[7];
    const float* Wu1 = (const float*)d_in[8];
    const float* bu1 = (const float*)d_in[9];
    const float* Wu2 = (const float*)d_in[10];
    const float* bu2 = (const float*)d_in[11];

    float* out_node = (float*)d_out;
    float* out_edge = out_node + (size_t)B * NN * CV;

    // ws layout
    unsigned short* ma_csr = (unsigned short*)d_ws;               // B*NE*16 bf16 (32 MB)
    unsigned short* mb_csr = ma_csr + (size_t)B * NE * 16;        // 32 MB
    float* agg_a = (float*)(mb_csr + (size_t)B * NE * 16);        // 8 MB
    float* agg_b = agg_a + (size_t)B * NN * CV;                   // 8 MB
    int* cnt_a   = (int*)(agg_b + (size_t)B * NN * CV);
    int* cnt_b   = cnt_a + NN;
    int* start_a = cnt_b + NN;
    int* start_b = start_a + NN;
    int* rank_a  = start_b + NN;
    int* rank_b  = rank_a + NE;

    hipMemsetAsync(cnt_a, 0, 2 * (size_t)NN * sizeof(int), stream);

    count_kernel<<<NE / 256, 256, 0, stream>>>(ca, cb, cnt_a, cnt_b, rank_a, rank_b);
    scan_kernel<<<2, 1024, 0, stream>>>(cnt_a, start_a, cnt_b, start_b);
    edge_kernel<<<(B * NE) / 256, 256, 0, stream>>>(
        node_vals, edge_vals, ca, cb, rank_a, rank_b, start_a, start_b,
        Wm1, bm1, Wm2, bm2, out_edge, ma_csr, mb_csr);
    agg_kernel<<<(B * NN) / 8, 256, 0, stream>>>(
        ma_csr, mb_csr, start_a, start_b, cnt_a, cnt_b, agg_a, agg_b);
    node_kernel<<<(B * NN) / 256, 256, 0, stream>>>(
        node_vals, agg_a, agg_b, Wu1, bu1, Wu2, bu2, out_node);
}

// Round 6
// 337.594 us; speedup vs baseline: 5.8861x; 1.0736x over previous
//
#include <hip/hip_runtime.h>
#include <hip/hip_bf16.h>
#include <cstdint>
#include <cstddef>

#define B 4
#define NN 32768
#define NE 262144
#define CV 16
#define CE 16
#define HID 64
#define CM 48   // 2*CV + CE
#define HS 72   // LDS row stride in bf16 elems (144 B)

using frag  = __attribute__((ext_vector_type(8))) short;
using f32x4 = __attribute__((ext_vector_type(4))) float;

__device__ __forceinline__ float fast_tanh(float x) {
    float e = __expf(2.0f * x);
    return 1.0f - 2.0f / (e + 1.0f);
}

__device__ __forceinline__ unsigned short f2bf(float x) {
    union { float f; unsigned u; } v; v.f = x;
    unsigned r = (v.u + 0x7FFFu + ((v.u >> 16) & 1u)) >> 16;
    return (unsigned short)r;
}

__device__ __forceinline__ float bf2f(unsigned short x) {
    union { unsigned u; float f; } v; v.u = ((unsigned)x) << 16;
    return v.f;
}

__device__ __forceinline__ unsigned pk2bf(float lo, float hi) {
    union { __hip_bfloat162 h; unsigned u; } v;
    v.h = __float22bfloat162_rn(make_float2(lo, hi));
    return v.u;
}

// ---------------- degree counts + per-edge rank + weight fragment prepack ----------------
// pW1[((mt*2+ks)*64+lane)*8+j] = W1t[mt*16+(lane&15)][ks*32+(lane>>4)*8+j]
//   where W1t[m][k] = k<48 ? Wm1[k*64+m] : (k==48 ? bm1[m] : 0)   (bias folded, K pad 48->64)
// pW2 likewise from W2t[m][k] = Wm2[k*48+m]  (mt 0..2)
__global__ __launch_bounds__(256) void count_kernel(
    const int* __restrict__ ca, const int* __restrict__ cb,
    int* __restrict__ cnt_a, int* __restrict__ cnt_b,
    int* __restrict__ rank_a, int* __restrict__ rank_b,
    const float* __restrict__ Wm1, const float* __restrict__ bm1,
    const float* __restrict__ Wm2,
    unsigned short* __restrict__ pW1, unsigned short* __restrict__ pW2)
{
    int i = blockIdx.x * 256 + threadIdx.x;
    rank_a[i] = atomicAdd(&cnt_a[ca[i]], 1);
    rank_b[i] = atomicAdd(&cnt_b[cb[i]], 1);

    if (blockIdx.x == 0) {
        for (int x = threadIdx.x; x < 4 * 2 * 64 * 8; x += 256) {
            int j = x & 7, lane = (x >> 3) & 63, ks = (x >> 9) & 1, mt = x >> 10;
            int m = mt * 16 + (lane & 15);
            int k = ks * 32 + (lane >> 4) * 8 + j;
            float w = (k < 48) ? Wm1[k * 64 + m] : (k == 48 ? bm1[m] : 0.0f);
            pW1[x] = f2bf(w);
        }
    } else if (blockIdx.x == 1) {
        for (int x = threadIdx.x; x < 3 * 2 * 64 * 8; x += 256) {
            int j = x & 7, lane = (x >> 3) & 63, ks = (x >> 9) & 1, mt = x >> 10;
            int m = mt * 16 + (lane & 15);
            int k = ks * 32 + (lane >> 4) * 8 + j;
            pW2[x] = f2bf(Wm2[k * 48 + m]);
        }
    }
}

// ---------------- exclusive prefix sum over NN bins (2 blocks: a and b) ----------------
__global__ __launch_bounds__(1024) void scan_kernel(
    const int* __restrict__ cnt_a, int* __restrict__ start_a,
    const int* __restrict__ cnt_b, int* __restrict__ start_b)
{
    const int* cnt = (blockIdx.x == 0) ? cnt_a : cnt_b;
    int* start     = (blockIdx.x == 0) ? start_a : start_b;

    __shared__ int s[1024];
    int t = threadIdx.x;
    int base = t * 32;
    int local[32];
    int sum = 0;
#pragma unroll
    for (int i = 0; i < 32; i++) { local[i] = cnt[base + i]; sum += local[i]; }
    s[t] = sum;
    __syncthreads();
    for (int off = 1; off < 1024; off <<= 1) {
        int add = (t >= off) ? s[t - off] : 0;
        __syncthreads();
        s[t] += add;
        __syncthreads();
    }
    int run = s[t] - sum;
#pragma unroll
    for (int i = 0; i < 32; i++) {
        start[base + i] = run;
        run += local[i];
    }
}

// ---------------- edge MLP via bf16 MFMA, register-resident weights ----------------
// Block = 256 edges (one batch), 4 waves; wave w owns edges [w*64, w*64+64).
// GEMM1: D1[hid][edge] = W1t @ Ht ; tanh -> T[edge][hid] in sH;
// GEMM2: D2[ch48][edge] = W2t @ Tt; m transposed через sH -> full-sector CSR stores.
__global__ __launch_bounds__(256) void edge_kernel(
    const float* __restrict__ node_vals, const float* __restrict__ edge_vals,
    const int* __restrict__ ca, const int* __restrict__ cb,
    const int* __restrict__ rank_a, const int* __restrict__ rank_b,
    const int* __restrict__ start_a, const int* __restrict__ start_b,
    const unsigned short* __restrict__ pW1, const unsigned short* __restrict__ pW2,
    const float* __restrict__ bm2,
    float* __restrict__ out_edge,
    unsigned short* __restrict__ ma_csr, unsigned short* __restrict__ mb_csr)
{
    __shared__ unsigned short sH[256 * HS];   // H -> T -> m (in-place, barrier-protected)
    __shared__ float sb2f[CM];

    int t = threadIdx.x;
    int lane = t & 63;
    int wv   = t >> 6;
    int col  = lane & 15;
    int quad = lane >> 4;
    int erow = wv * 64;
    int cha  = quad * 4;

    // ---- weight fragments GEMM1: coalesced 16B loads, straight to registers ----
    frag w1f[4][2];
#pragma unroll
    for (int mt = 0; mt < 4; mt++)
#pragma unroll
        for (int ks = 0; ks < 2; ks++)
            w1f[mt][ks] = *(const frag*)&pW1[(((mt * 2 + ks) * 64) + lane) * 8];

    if (t < CM) sb2f[t] = bm2[t];

    // ---- stage H; keep CSR positions in registers ----
    size_t eb = (size_t)blockIdx.x * 256;
    int posx, posy;
    {
        size_t idx = eb + t;
        int e = (int)(idx & (NE - 1));
        int bb = (int)(idx >> 18);
        int na = ca[e], nb = cb[e];
        posx = start_a[na] + rank_a[e];
        posy = start_b[nb] + rank_b[e];
        float h[48];
        const float4* pA = (const float4*)(node_vals + ((size_t)bb * NN + na) * CV);
        const float4* pB = (const float4*)(node_vals + ((size_t)bb * NN + nb) * CV);
        const float4* pE = (const float4*)(edge_vals + idx * CE);
#pragma unroll
        for (int q = 0; q < 4; q++) {
            float4 va = pA[q];
            h[q*4+0] = va.x; h[q*4+1] = va.y; h[q*4+2] = va.z; h[q*4+3] = va.w;
            float4 vb = pB[q];
            h[16+q*4+0] = vb.x; h[16+q*4+1] = vb.y; h[16+q*4+2] = vb.z; h[16+q*4+3] = vb.w;
            float4 ve = pE[q];
            h[32+q*4+0] = ve.x; h[32+q*4+1] = ve.y; h[32+q*4+2] = ve.z; h[32+q*4+3] = ve.w;
        }
        unsigned pk[32];
#pragma unroll
        for (int q = 0; q < 24; q++) pk[q] = pk2bf(h[2*q], h[2*q+1]);
        pk[24] = 0x3F80u;   // k=48: 1.0 (bias row), k=49: 0
#pragma unroll
        for (int q = 25; q < 32; q++) pk[q] = 0;
        uint4* row = (uint4*)&sH[t * HS];
        const uint4* src = (const uint4*)pk;
#pragma unroll
        for (int q = 0; q < 8; q++) row[q] = src[q];
    }
    __syncthreads();   // (1) H ready

    // ---- GEMM1: D1[m=hid][n=edge] ----
    f32x4 acc1[4][4];
#pragma unroll
    for (int mt = 0; mt < 4; mt++)
#pragma unroll
        for (int nt = 0; nt < 4; nt++) acc1[mt][nt] = (f32x4){0.f, 0.f, 0.f, 0.f};

#pragma unroll
    for (int ks = 0; ks < 2; ks++) {
        frag bfr[4];
#pragma unroll
        for (int nt = 0; nt < 4; nt++)
            bfr[nt] = *(const frag*)&sH[(erow + nt*16 + col) * HS + ks*32 + quad*8];
#pragma unroll
        for (int mt = 0; mt < 4; mt++)
#pragma unroll
            for (int nt = 0; nt < 4; nt++)
                acc1[mt][nt] = __builtin_amdgcn_mfma_f32_16x16x32_bf16(w1f[mt][ks], bfr[nt], acc1[mt][nt], 0, 0, 0);
    }

    __syncthreads();   // (2) all GEMM1 reads of sH complete before overwrite

    // GEMM2 weight fragments (loaded late to cap VGPR peak; latency hides under tanh/barrier)
    frag w2f[3][2];
#pragma unroll
    for (int mt = 0; mt < 3; mt++)
#pragma unroll
        for (int ks = 0; ks < 2; ks++)
            w2f[mt][ks] = *(const frag*)&pW2[(((mt * 2 + ks) * 64) + lane) * 8];

    // ---- tanh -> T[edge][hid] in sH ----
#pragma unroll
    for (int nt = 0; nt < 4; nt++) {
        int row = erow + nt*16 + col;
#pragma unroll
        for (int mt = 0; mt < 4; mt++) {
            uint2 w;
            w.x = pk2bf(fast_tanh(acc1[mt][nt][0]), fast_tanh(acc1[mt][nt][1]));
            w.y = pk2bf(fast_tanh(acc1[mt][nt][2]), fast_tanh(acc1[mt][nt][3]));
            *(uint2*)&sH[row * HS + mt*16 + quad*4] = w;
        }
    }
    __syncthreads();   // (3) T ready

    // ---- GEMM2: D2[m=ch48][n=edge] ----
    f32x4 acc2[3][4];
#pragma unroll
    for (int mt = 0; mt < 3; mt++)
#pragma unroll
        for (int nt = 0; nt < 4; nt++) acc2[mt][nt] = (f32x4){0.f, 0.f, 0.f, 0.f};

#pragma unroll
    for (int ks = 0; ks < 2; ks++) {
        frag bfr[4];
#pragma unroll
        for (int nt = 0; nt < 4; nt++)
            bfr[nt] = *(const frag*)&sH[(erow + nt*16 + col) * HS + ks*32 + quad*8];
#pragma unroll
        for (int mt = 0; mt < 3; mt++)
#pragma unroll
            for (int nt = 0; nt < 4; nt++)
                acc2[mt][nt] = __builtin_amdgcn_mfma_f32_16x16x32_bf16(w2f[mt][ks], bfr[nt], acc2[mt][nt], 0, 0, 0);
    }

    // ---- edge residual (fp32, coalesced; uses acc2 layout directly) ----
#pragma unroll
    for (int nt = 0; nt < 4; nt++) {
        int le = erow + nt*16 + col;
        size_t o = (eb + le) * CE + cha;
        float4 ev = *(const float4*)&edge_vals[o];
        float4 ov;
        ov.x = ev.x + acc2[2][nt][0] + sb2f[32+cha+0];
        ov.y = ev.y + acc2[2][nt][1] + sb2f[32+cha+1];
        ov.z = ev.z + acc2[2][nt][2] + sb2f[32+cha+2];
        ov.w = ev.w + acc2[2][nt][3] + sb2f[32+cha+3];
        *(float4*)&out_edge[o] = ov;
    }

    __syncthreads();   // (4) all GEMM2 reads of sH complete before overwrite

    // ---- pack m_a|m_b (bias added, bf16) into sH rows: [edge][32ch] ----
#pragma unroll
    for (int nt = 0; nt < 4; nt++) {
        int row = erow + nt*16 + col;
        uint2 wa;
        wa.x = pk2bf(acc2[0][nt][0] + sb2f[cha+0], acc2[0][nt][1] + sb2f[cha+1]);
        wa.y = pk2bf(acc2[0][nt][2] + sb2f[cha+2], acc2[0][nt][3] + sb2f[cha+3]);
        *(uint2*)&sH[row * HS + cha] = wa;
        uint2 wb;
        wb.x = pk2bf(acc2[1][nt][0] + sb2f[16+cha+0], acc2[1][nt][1] + sb2f[16+cha+1]);
        wb.y = pk2bf(acc2[1][nt][2] + sb2f[16+cha+2], acc2[1][nt][3] + sb2f[16+cha+3]);
        *(uint2*)&sH[row * HS + 16 + cha] = wb;
    }
    __syncthreads();   // (5) m rows ready

    // ---- full-sector CSR scatter: thread t owns edge t (pos in registers) ----
    {
        int bb = (int)((eb + t) >> 18);
        uint4 a0 = *(const uint4*)&sH[t * HS + 0];
        uint4 a1 = *(const uint4*)&sH[t * HS + 8];
        uint4 b0 = *(const uint4*)&sH[t * HS + 16];
        uint4 b1 = *(const uint4*)&sH[t * HS + 24];
        unsigned short* pa = &ma_csr[((size_t)bb * NE + posx) * 16];
        *(uint4*)(pa + 0) = a0;
        *(uint4*)(pa + 8) = a1;
        unsigned short* pb = &mb_csr[((size_t)bb * NE + posy) * 16];
        *(uint4*)(pb + 0) = b0;
        *(uint4*)(pb + 8) = b1;
    }
}

// ---------------- fused segmented-mean aggregation + node MLP + residual ----------------
// Block = 256 nodes of one batch. Phase 1: teams of 32 lanes stream contiguous CSR
// segments -> aggL in LDS (stride 33: conflict-free phase-2 reads). Phase 2: node MLP.
__global__ __launch_bounds__(256) void aggnode_kernel(
    const float* __restrict__ node_vals,
    const unsigned short* __restrict__ ma_csr, const unsigned short* __restrict__ mb_csr,
    const int* __restrict__ start_a, const int* __restrict__ start_b,
    const int* __restrict__ cnt_a, const int* __restrict__ cnt_b,
    const float* __restrict__ Wu1, const float* __restrict__ bu1,
    const float* __restrict__ Wu2, const float* __restrict__ bu2,
    float* __restrict__ out_node)
{
    __shared__ float sW1[HID * CM];    // sW1[k*CM+i] = Wu1[i*HID+k]
    __shared__ float sW2[HID * CV];
    __shared__ float sb1[HID];
    __shared__ float sb2[CV];
    __shared__ float aggL[256][33];    // ch 0..15 = agg_a, 16..31 = agg_b; col 32 pad

    int t = threadIdx.x;
    for (int x = t; x < HID * CM; x += 256) {
        int k = x / CM, i = x - k * CM;
        sW1[x] = Wu1[i * HID + k];
    }
    for (int x = t; x < HID * CV; x += 256) sW2[x] = Wu2[x];
    if (t < HID) sb1[t] = bu1[t];
    if (t < CV)  sb2[t] = bu2[t];

    int g0 = blockIdx.x * 256;          // first (b*NN+n) of this block
    int b  = g0 >> 15;                  // batch, block-uniform

    // ---- phase 1: aggregate 256 nodes, 8 per pass ----
    int team = t >> 5;
    int half = (t >> 4) & 1;
    int l16  = t & 15;
    int e_off = l16 >> 2;
    int cg    = l16 & 3;

    const unsigned short* mcsr = half ? mb_csr : ma_csr;
    const int* stp  = half ? start_b : start_a;
    const int* cntp = half ? cnt_b   : cnt_a;

    for (int pass = 0; pass < 32; pass++) {
        int ln = pass * 8 + team;        // local node 0..255
        int n  = (g0 + ln) & (NN - 1);
        int d  = cntp[n];
        int s  = stp[n];
        const unsigned short* base = mcsr + ((size_t)b * NE + s) * 16 + cg * 4;
        float s0 = 0.f, s1 = 0.f, s2 = 0.f, s3 = 0.f;
        for (int k = e_off; k < d; k += 4) {
            uint2 v = *(const uint2*)(base + (size_t)k * 16);
            s0 += bf2f((unsigned short)(v.x & 0xFFFFu));
            s1 += bf2f((unsigned short)(v.x >> 16));
            s2 += bf2f((unsigned short)(v.y & 0xFFFFu));
            s3 += bf2f((unsigned short)(v.y >> 16));
        }
        s0 += __shfl_xor(s0, 4); s1 += __shfl_xor(s1, 4);
        s2 += __shfl_xor(s2, 4); s3 += __shfl_xor(s3, 4);
        s0 += __shfl_xor(s0, 8); s1 += __shfl_xor(s1, 8);
        s2 += __shfl_xor(s2, 8); s3 += __shfl_xor(s3, 8);
        if (e_off == 0) {
            float inv = 1.0f / (float)max(d, 1);
            float* dst = &aggL[ln][half * 16 + cg * 4];
            dst[0] = s0 * inv; dst[1] = s1 * inv; dst[2] = s2 * inv; dst[3] = s3 * inv;
        }
    }
    __syncthreads();

    // ---- phase 2: node MLP for node g0 + t ----
    int idx = g0 + t;
    float u[CM];
#pragma unroll
    for (int i = 0; i < 32; i++) u[i] = aggL[t][i];
    const float4* pn = (const float4*)(node_vals + (size_t)idx * CV);
#pragma unroll
    for (int q = 0; q < 4; q++) {
        float4 vn = pn[q];
        u[32+q*4+0] = vn.x; u[32+q*4+1] = vn.y; u[32+q*4+2] = vn.z; u[32+q*4+3] = vn.w;
    }

    float o[CV];
#pragma unroll
    for (int j = 0; j < CV; j++) o[j] = sb2[j];

    for (int k = 0; k < HID; k++) {
        float acc = sb1[k];
        const float* w1 = &sW1[k * CM];
#pragma unroll
        for (int i = 0; i < CM; i++) acc = fmaf(u[i], w1[i], acc);
        float th = fast_tanh(acc);
        const float* w2 = &sW2[k * CV];
#pragma unroll
        for (int j = 0; j < CV; j++) o[j] = fmaf(th, w2[j], o[j]);
    }

    float4* on = (float4*)(out_node + (size_t)idx * CV);
#pragma unroll
    for (int q = 0; q < 4; q++) {
        on[q] = make_float4(u[32+q*4+0] + o[q*4+0],
                            u[32+q*4+1] + o[q*4+1],
                            u[32+q*4+2] + o[q*4+2],
                            u[32+q*4+3] + o[q*4+3]);
    }
}

extern "C" void kernel_launch(void* const* d_in, const int* in_sizes, int n_in,
                              void* d_out, int out_size, void* d_ws, size_t ws_size,
                              hipStream_t stream) {
    const float* node_vals = (const float*)d_in[0];
    const float* edge_vals = (const float*)d_in[1];
    const int*   ca        = (const int*)d_in[2];
    const int*   cb        = (const int*)d_in[3];
    const float* Wm1 = (const float*)d_in[4];
    const float* bm1 = (const float*)d_in[5];
    const float* Wm2 = (const float*)d_in[6];
    const float* bm2 = (const float*)d_in[7];
    const float* Wu1 = (const float*)d_in[8];
    const float* bu1 = (const float*)d_in[9];
    const float* Wu2 = (const float*)d_in[10];
    const float* bu2 = (const float*)d_in[11];

    float* out_node = (float*)d_out;
    float* out_edge = out_node + (size_t)B * NN * CV;

    // ws layout
    unsigned short* ma_csr = (unsigned short*)d_ws;               // B*NE*16 bf16 (32 MB)
    unsigned short* mb_csr = ma_csr + (size_t)B * NE * 16;        // 32 MB
    int* cnt_a   = (int*)(mb_csr + (size_t)B * NE * 16);
    int* cnt_b   = cnt_a + NN;
    int* start_a = cnt_b + NN;
    int* start_b = start_a + NN;
    int* rank_a  = start_b + NN;
    int* rank_b  = rank_a + NE;
    unsigned short* pW1 = (unsigned short*)(rank_b + NE);         // 4096 bf16
    unsigned short* pW2 = pW1 + 4096;                             // 3072 bf16

    hipMemsetAsync(cnt_a, 0, 2 * (size_t)NN * sizeof(int), stream);

    count_kernel<<<NE / 256, 256, 0, stream>>>(
        ca, cb, cnt_a, cnt_b, rank_a, rank_b, Wm1, bm1, Wm2, pW1, pW2);
    scan_kernel<<<2, 1024, 0, stream>>>(cnt_a, start_a, cnt_b, start_b);
    edge_kernel<<<(B * NE) / 256, 256, 0, stream>>>(
        node_vals, edge_vals, ca, cb, rank_a, rank_b, start_a, start_b,
        pW1, pW2, bm2, out_edge, ma_csr, mb_csr);
    aggnode_kernel<<<(B * NN) / 256, 256, 0, stream>>>(
        node_vals, ma_csr, mb_csr, start_a, start_b, cnt_a, cnt_b,
        Wu1, bu1, Wu2, bu2, out_node);
}

// Round 7
// 323.177 us; speedup vs baseline: 6.1487x; 1.0446x over previous
//
#include <hip/hip_runtime.h>
#include <hip/hip_bf16.h>
#include <cstdint>
#include <cstddef>

#define B 4
#define NN 32768
#define NE 262144
#define CV 16
#define CE 16
#define HID 64
#define CM 48   // 2*CV + CE
#define HS 72   // LDS row stride in bf16 elems (144 B)

using frag  = __attribute__((ext_vector_type(8))) short;
using f32x4 = __attribute__((ext_vector_type(4))) float;

__device__ __forceinline__ float fast_tanh(float x) {
    float e = __expf(2.0f * x);
    return 1.0f - 2.0f / (e + 1.0f);
}

__device__ __forceinline__ unsigned short f2bf(float x) {
    union { float f; unsigned u; } v; v.f = x;
    unsigned r = (v.u + 0x7FFFu + ((v.u >> 16) & 1u)) >> 16;
    return (unsigned short)r;
}

__device__ __forceinline__ float bf2f(unsigned short x) {
    union { unsigned u; float f; } v; v.u = ((unsigned)x) << 16;
    return v.f;
}

__device__ __forceinline__ unsigned pk2bf(float lo, float hi) {
    union { __hip_bfloat162 h; unsigned u; } v;
    v.h = __float22bfloat162_rn(make_float2(lo, hi));
    return v.u;
}

// ---------------- degree counts + per-edge rank + weight fragment prepack ----------------
__global__ __launch_bounds__(256) void count_kernel(
    const int* __restrict__ ca, const int* __restrict__ cb,
    int* __restrict__ cnt_a, int* __restrict__ cnt_b,
    int* __restrict__ rank_a, int* __restrict__ rank_b,
    const float* __restrict__ Wm1, const float* __restrict__ bm1,
    const float* __restrict__ Wm2,
    unsigned short* __restrict__ pW1, unsigned short* __restrict__ pW2)
{
    int i = blockIdx.x * 256 + threadIdx.x;
    rank_a[i] = atomicAdd(&cnt_a[ca[i]], 1);
    rank_b[i] = atomicAdd(&cnt_b[cb[i]], 1);

    if (blockIdx.x == 0) {
        for (int x = threadIdx.x; x < 4 * 2 * 64 * 8; x += 256) {
            int j = x & 7, lane = (x >> 3) & 63, ks = (x >> 9) & 1, mt = x >> 10;
            int m = mt * 16 + (lane & 15);
            int k = ks * 32 + (lane >> 4) * 8 + j;
            float w = (k < 48) ? Wm1[k * 64 + m] : (k == 48 ? bm1[m] : 0.0f);
            pW1[x] = f2bf(w);
        }
    } else if (blockIdx.x == 1) {
        for (int x = threadIdx.x; x < 3 * 2 * 64 * 8; x += 256) {
            int j = x & 7, lane = (x >> 3) & 63, ks = (x >> 9) & 1, mt = x >> 10;
            int m = mt * 16 + (lane & 15);
            int k = ks * 32 + (lane >> 4) * 8 + j;
            pW2[x] = f2bf(Wm2[k * 48 + m]);
        }
    }
}

// ---------------- exclusive prefix sum over NN bins (2 blocks: a and b) ----------------
__global__ __launch_bounds__(1024) void scan_kernel(
    const int* __restrict__ cnt_a, int* __restrict__ start_a,
    const int* __restrict__ cnt_b, int* __restrict__ start_b)
{
    const int* cnt = (blockIdx.x == 0) ? cnt_a : cnt_b;
    int* start     = (blockIdx.x == 0) ? start_a : start_b;

    __shared__ int s[1024];
    int t = threadIdx.x;
    int base = t * 32;
    int local[32];
    int sum = 0;
#pragma unroll
    for (int i = 0; i < 32; i++) { local[i] = cnt[base + i]; sum += local[i]; }
    s[t] = sum;
    __syncthreads();
    for (int off = 1; off < 1024; off <<= 1) {
        int add = (t >= off) ? s[t - off] : 0;
        __syncthreads();
        s[t] += add;
        __syncthreads();
    }
    int run = s[t] - sum;
#pragma unroll
    for (int i = 0; i < 32; i++) {
        start[base + i] = run;
        run += local[i];
    }
}

// ---------------- edge MLP via bf16 MFMA, register-resident weights ----------------
// (identical to round 6 — isolate the tail changes this round)
__global__ __launch_bounds__(256) void edge_kernel(
    const float* __restrict__ node_vals, const float* __restrict__ edge_vals,
    const int* __restrict__ ca, const int* __restrict__ cb,
    const int* __restrict__ rank_a, const int* __restrict__ rank_b,
    const int* __restrict__ start_a, const int* __restrict__ start_b,
    const unsigned short* __restrict__ pW1, const unsigned short* __restrict__ pW2,
    const float* __restrict__ bm2,
    float* __restrict__ out_edge,
    unsigned short* __restrict__ ma_csr, unsigned short* __restrict__ mb_csr)
{
    __shared__ unsigned short sH[256 * HS];   // H -> T -> m (in-place, barrier-protected)
    __shared__ float sb2f[CM];

    int t = threadIdx.x;
    int lane = t & 63;
    int wv   = t >> 6;
    int col  = lane & 15;
    int quad = lane >> 4;
    int erow = wv * 64;
    int cha  = quad * 4;

    frag w1f[4][2];
#pragma unroll
    for (int mt = 0; mt < 4; mt++)
#pragma unroll
        for (int ks = 0; ks < 2; ks++)
            w1f[mt][ks] = *(const frag*)&pW1[(((mt * 2 + ks) * 64) + lane) * 8];

    if (t < CM) sb2f[t] = bm2[t];

    size_t eb = (size_t)blockIdx.x * 256;
    int posx, posy;
    {
        size_t idx = eb + t;
        int e = (int)(idx & (NE - 1));
        int bb = (int)(idx >> 18);
        int na = ca[e], nb = cb[e];
        posx = start_a[na] + rank_a[e];
        posy = start_b[nb] + rank_b[e];
        float h[48];
        const float4* pA = (const float4*)(node_vals + ((size_t)bb * NN + na) * CV);
        const float4* pB = (const float4*)(node_vals + ((size_t)bb * NN + nb) * CV);
        const float4* pE = (const float4*)(edge_vals + idx * CE);
#pragma unroll
        for (int q = 0; q < 4; q++) {
            float4 va = pA[q];
            h[q*4+0] = va.x; h[q*4+1] = va.y; h[q*4+2] = va.z; h[q*4+3] = va.w;
            float4 vb = pB[q];
            h[16+q*4+0] = vb.x; h[16+q*4+1] = vb.y; h[16+q*4+2] = vb.z; h[16+q*4+3] = vb.w;
            float4 ve = pE[q];
            h[32+q*4+0] = ve.x; h[32+q*4+1] = ve.y; h[32+q*4+2] = ve.z; h[32+q*4+3] = ve.w;
        }
        unsigned pk[32];
#pragma unroll
        for (int q = 0; q < 24; q++) pk[q] = pk2bf(h[2*q], h[2*q+1]);
        pk[24] = 0x3F80u;
#pragma unroll
        for (int q = 25; q < 32; q++) pk[q] = 0;
        uint4* row = (uint4*)&sH[t * HS];
        const uint4* src = (const uint4*)pk;
#pragma unroll
        for (int q = 0; q < 8; q++) row[q] = src[q];
    }
    __syncthreads();   // (1) H ready

    f32x4 acc1[4][4];
#pragma unroll
    for (int mt = 0; mt < 4; mt++)
#pragma unroll
        for (int nt = 0; nt < 4; nt++) acc1[mt][nt] = (f32x4){0.f, 0.f, 0.f, 0.f};

#pragma unroll
    for (int ks = 0; ks < 2; ks++) {
        frag bfr[4];
#pragma unroll
        for (int nt = 0; nt < 4; nt++)
            bfr[nt] = *(const frag*)&sH[(erow + nt*16 + col) * HS + ks*32 + quad*8];
#pragma unroll
        for (int mt = 0; mt < 4; mt++)
#pragma unroll
            for (int nt = 0; nt < 4; nt++)
                acc1[mt][nt] = __builtin_amdgcn_mfma_f32_16x16x32_bf16(w1f[mt][ks], bfr[nt], acc1[mt][nt], 0, 0, 0);
    }

    __syncthreads();   // (2) GEMM1 reads done

    frag w2f[3][2];
#pragma unroll
    for (int mt = 0; mt < 3; mt++)
#pragma unroll
        for (int ks = 0; ks < 2; ks++)
            w2f[mt][ks] = *(const frag*)&pW2[(((mt * 2 + ks) * 64) + lane) * 8];

#pragma unroll
    for (int nt = 0; nt < 4; nt++) {
        int row = erow + nt*16 + col;
#pragma unroll
        for (int mt = 0; mt < 4; mt++) {
            uint2 w;
            w.x = pk2bf(fast_tanh(acc1[mt][nt][0]), fast_tanh(acc1[mt][nt][1]));
            w.y = pk2bf(fast_tanh(acc1[mt][nt][2]), fast_tanh(acc1[mt][nt][3]));
            *(uint2*)&sH[row * HS + mt*16 + quad*4] = w;
        }
    }
    __syncthreads();   // (3) T ready

    f32x4 acc2[3][4];
#pragma unroll
    for (int mt = 0; mt < 3; mt++)
#pragma unroll
        for (int nt = 0; nt < 4; nt++) acc2[mt][nt] = (f32x4){0.f, 0.f, 0.f, 0.f};

#pragma unroll
    for (int ks = 0; ks < 2; ks++) {
        frag bfr[4];
#pragma unroll
        for (int nt = 0; nt < 4; nt++)
            bfr[nt] = *(const frag*)&sH[(erow + nt*16 + col) * HS + ks*32 + quad*8];
#pragma unroll
        for (int mt = 0; mt < 3; mt++)
#pragma unroll
            for (int nt = 0; nt < 4; nt++)
                acc2[mt][nt] = __builtin_amdgcn_mfma_f32_16x16x32_bf16(w2f[mt][ks], bfr[nt], acc2[mt][nt], 0, 0, 0);
    }

#pragma unroll
    for (int nt = 0; nt < 4; nt++) {
        int le = erow + nt*16 + col;
        size_t o = (eb + le) * CE + cha;
        float4 ev = *(const float4*)&edge_vals[o];
        float4 ov;
        ov.x = ev.x + acc2[2][nt][0] + sb2f[32+cha+0];
        ov.y = ev.y + acc2[2][nt][1] + sb2f[32+cha+1];
        ov.z = ev.z + acc2[2][nt][2] + sb2f[32+cha+2];
        ov.w = ev.w + acc2[2][nt][3] + sb2f[32+cha+3];
        *(float4*)&out_edge[o] = ov;
    }

    __syncthreads();   // (4) GEMM2 reads done

#pragma unroll
    for (int nt = 0; nt < 4; nt++) {
        int row = erow + nt*16 + col;
        uint2 wa;
        wa.x = pk2bf(acc2[0][nt][0] + sb2f[cha+0], acc2[0][nt][1] + sb2f[cha+1]);
        wa.y = pk2bf(acc2[0][nt][2] + sb2f[cha+2], acc2[0][nt][3] + sb2f[cha+3]);
        *(uint2*)&sH[row * HS + cha] = wa;
        uint2 wb;
        wb.x = pk2bf(acc2[1][nt][0] + sb2f[16+cha+0], acc2[1][nt][1] + sb2f[16+cha+1]);
        wb.y = pk2bf(acc2[1][nt][2] + sb2f[16+cha+2], acc2[1][nt][3] + sb2f[16+cha+3]);
        *(uint2*)&sH[row * HS + 16 + cha] = wb;
    }
    __syncthreads();   // (5) m rows ready

    {
        int bb = (int)((eb + t) >> 18);
        uint4 a0 = *(const uint4*)&sH[t * HS + 0];
        uint4 a1 = *(const uint4*)&sH[t * HS + 8];
        uint4 b0 = *(const uint4*)&sH[t * HS + 16];
        uint4 b1 = *(const uint4*)&sH[t * HS + 24];
        unsigned short* pa = &ma_csr[((size_t)bb * NE + posx) * 16];
        *(uint4*)(pa + 0) = a0;
        *(uint4*)(pa + 8) = a1;
        unsigned short* pb = &mb_csr[((size_t)bb * NE + posy) * 16];
        *(uint4*)(pb + 0) = b0;
        *(uint4*)(pb + 8) = b1;
    }
}

// ---------------- segmented mean over contiguous CSR messages ----------------
// Block 256 = 8 teams x 32 lanes; team = one (b,n); half 0=a,1=b (16 lanes each).
// Lane l16 = eoff*2 + chunk: uint4 (16B = 8 ch) of edge s+k, chunk selects ch 0-7/8-15.
// 16 lanes cover 8 edges (256B contiguous) per iteration; avg degree 8 -> ~1 iter.
__global__ __launch_bounds__(256) void agg_kernel(
    const unsigned short* __restrict__ ma_csr, const unsigned short* __restrict__ mb_csr,
    const int* __restrict__ start_a, const int* __restrict__ start_b,
    const int* __restrict__ cnt_a, const int* __restrict__ cnt_b,
    float* __restrict__ agg_a, float* __restrict__ agg_b)
{
    int t = threadIdx.x;
    int team = t >> 5;
    int half = (t >> 4) & 1;
    int l16  = t & 15;
    int eoff  = l16 >> 1;      // 0..7: edge offset within pass
    int chunk = l16 & 1;       // 0: ch0-7, 1: ch8-15
    int g = blockIdx.x * 8 + team;      // g = b*NN + n
    int n = g & (NN - 1);
    int b = g >> 15;

    const unsigned short* mcsr = half ? mb_csr : ma_csr;
    const int* stp  = half ? start_b : start_a;
    const int* cntp = half ? cnt_b   : cnt_a;
    float* aggp     = half ? agg_b   : agg_a;

    int d = cntp[n];
    int s = stp[n];
    const unsigned short* base = mcsr + ((size_t)b * NE + s) * 16 + chunk * 8;

    float acc[8] = {0.f, 0.f, 0.f, 0.f, 0.f, 0.f, 0.f, 0.f};
    for (int k = eoff; k < d; k += 8) {
        uint4 v = *(const uint4*)(base + (size_t)k * 16);
        acc[0] += bf2f((unsigned short)(v.x & 0xFFFFu));
        acc[1] += bf2f((unsigned short)(v.x >> 16));
        acc[2] += bf2f((unsigned short)(v.y & 0xFFFFu));
        acc[3] += bf2f((unsigned short)(v.y >> 16));
        acc[4] += bf2f((unsigned short)(v.z & 0xFFFFu));
        acc[5] += bf2f((unsigned short)(v.z >> 16));
        acc[6] += bf2f((unsigned short)(v.w & 0xFFFFu));
        acc[7] += bf2f((unsigned short)(v.w >> 16));
    }
    // reduce across eoff (lane bits 1..3); chunk bit preserved
#pragma unroll
    for (int m = 2; m <= 8; m <<= 1) {
#pragma unroll
        for (int i = 0; i < 8; i++) acc[i] += __shfl_xor(acc[i], m);
    }

    if (eoff == 0) {
        float inv = 1.0f / (float)max(d, 1);
        float4 r0, r1;
        r0.x = acc[0]*inv; r0.y = acc[1]*inv; r0.z = acc[2]*inv; r0.w = acc[3]*inv;
        r1.x = acc[4]*inv; r1.y = acc[5]*inv; r1.z = acc[6]*inv; r1.w = acc[7]*inv;
        float* dst = &aggp[(size_t)g * CV + chunk * 8];
        *(float4*)(dst + 0) = r0;
        *(float4*)(dst + 4) = r1;
    }
}

// ---------------- node MLP + residual ----------------
__global__ __launch_bounds__(256) void node_kernel(
    const float* __restrict__ node_vals,
    const float* __restrict__ agg_a, const float* __restrict__ agg_b,
    const float* __restrict__ Wu1, const float* __restrict__ bu1,
    const float* __restrict__ Wu2, const float* __restrict__ bu2,
    float* __restrict__ out_node)
{
    __shared__ float sW1[HID * CM];
    __shared__ float sW2[HID * CV];
    __shared__ float sb1[HID];
    __shared__ float sb2[CV];

    int t = threadIdx.x;
    for (int x = t; x < HID * CM; x += 256) {
        int k = x / CM, i = x - k * CM;
        sW1[x] = Wu1[i * HID + k];
    }
    for (int x = t; x < HID * CV; x += 256) sW2[x] = Wu2[x];
    if (t < HID) sb1[t] = bu1[t];
    if (t < CV)  sb2[t] = bu2[t];
    __syncthreads();

    int idx = blockIdx.x * 256 + t;

    float u[CM];
    const float4* pa = (const float4*)(agg_a + (size_t)idx * CV);
    const float4* pb = (const float4*)(agg_b + (size_t)idx * CV);
    const float4* pn = (const float4*)(node_vals + (size_t)idx * CV);
#pragma unroll
    for (int q = 0; q < 4; q++) {
        float4 va = pa[q];
        u[q*4+0] = va.x; u[q*4+1] = va.y; u[q*4+2] = va.z; u[q*4+3] = va.w;
        float4 vb = pb[q];
        u[16+q*4+0] = vb.x; u[16+q*4+1] = vb.y; u[16+q*4+2] = vb.z; u[16+q*4+3] = vb.w;
        float4 vn = pn[q];
        u[32+q*4+0] = vn.x; u[32+q*4+1] = vn.y; u[32+q*4+2] = vn.z; u[32+q*4+3] = vn.w;
    }

    float o[CV];
#pragma unroll
    for (int j = 0; j < CV; j++) o[j] = sb2[j];

    for (int k = 0; k < HID; k++) {
        float acc = sb1[k];
        const float* w1 = &sW1[k * CM];
#pragma unroll
        for (int i = 0; i < CM; i++) acc = fmaf(u[i], w1[i], acc);
        float th = fast_tanh(acc);
        const float* w2 = &sW2[k * CV];
#pragma unroll
        for (int j = 0; j < CV; j++) o[j] = fmaf(th, w2[j], o[j]);
    }

    float4* on = (float4*)(out_node + (size_t)idx * CV);
#pragma unroll
    for (int q = 0; q < 4; q++) {
        on[q] = make_float4(u[32+q*4+0] + o[q*4+0],
                            u[32+q*4+1] + o[q*4+1],
                            u[32+q*4+2] + o[q*4+2],
                            u[32+q*4+3] + o[q*4+3]);
    }
}

extern "C" void kernel_launch(void* const* d_in, const int* in_sizes, int n_in,
                              void* d_out, int out_size, void* d_ws, size_t ws_size,
                              hipStream_t stream) {
    const float* node_vals = (const float*)d_in[0];
    const float* edge_vals = (const float*)d_in[1];
    const int*   ca        = (const int*)d_in[2];
    const int*   cb        = (const int*)d_in[3];
    const float* Wm1 = (const float*)d_in[4];
    const float* bm1 = (const float*)d_in[5];
    const float* Wm2 = (const float*)d_in[6];
    const float* bm2 = (const float*)d_in[7];
    const float* Wu1 = (const float*)d_in[8];
    const float* bu1 = (const float*)d_in[9];
    const float* Wu2 = (const float*)d_in[10];
    const float* bu2 = (const float*)d_in[11];

    float* out_node = (float*)d_out;
    float* out_edge = out_node + (size_t)B * NN * CV;

    // ws layout
    unsigned short* ma_csr = (unsigned short*)d_ws;               // B*NE*16 bf16 (32 MB)
    unsigned short* mb_csr = ma_csr + (size_t)B * NE * 16;        // 32 MB
    float* agg_a = (float*)(mb_csr + (size_t)B * NE * 16);        // 8 MB
    float* agg_b = agg_a + (size_t)B * NN * CV;                   // 8 MB
    int* cnt_a   = (int*)(agg_b + (size_t)B * NN * CV);
    int* cnt_b   = cnt_a + NN;
    int* start_a = cnt_b + NN;
    int* start_b = start_a + NN;
    int* rank_a  = start_b + NN;
    int* rank_b  = rank_a + NE;
    unsigned short* pW1 = (unsigned short*)(rank_b + NE);         // 4096 bf16
    unsigned short* pW2 = pW1 + 4096;                             // 3072 bf16

    hipMemsetAsync(cnt_a, 0, 2 * (size_t)NN * sizeof(int), stream);

    count_kernel<<<NE / 256, 256, 0, stream>>>(
        ca, cb, cnt_a, cnt_b, rank_a, rank_b, Wm1, bm1, Wm2, pW1, pW2);
    scan_kernel<<<2, 1024, 0, stream>>>(cnt_a, start_a, cnt_b, start_b);
    edge_kernel<<<(B * NE) / 256, 256, 0, stream>>>(
        node_vals, edge_vals, ca, cb, rank_a, rank_b, start_a, start_b,
        pW1, pW2, bm2, out_edge, ma_csr, mb_csr);
    agg_kernel<<<(B * NN) / 8, 256, 0, stream>>>(
        ma_csr, mb_csr, start_a, start_b, cnt_a, cnt_b, agg_a, agg_b);
    node_kernel<<<(B * NN) / 256, 256, 0, stream>>>(
        node_vals, agg_a, agg_b, Wu1, bu1, Wu2, bu2, out_node);
}